// Round 1
// baseline (507.575 us; speedup 1.0000x reference)
//
#include <hip/hip_runtime.h>
#include <cstddef>

#define BB 8
#define TT 1024
#define DD 512
#define HH 8
#define HD 64
// rows = B*T = 8192

// ---------------- K1: vq[h][d] = sum_j Wq[d, h*64+j]*w_mlp[64+j]; qs_bias[h] ----
__global__ __launch_bounds__(256) void prep_kernel(
    const float* __restrict__ Wq, const float* __restrict__ bq,
    const float* __restrict__ wm,
    float* __restrict__ vq, float* __restrict__ qs_bias)
{
    int idx = blockIdx.x * 256 + threadIdx.x;   // 0..4095
    int h = idx >> 9, d = idx & 511;
    float s = 0.f;
    #pragma unroll 8
    for (int j = 0; j < HD; ++j)
        s = fmaf(Wq[(size_t)d * DD + h * HD + j], wm[HD + j], s);
    vq[h * DD + d] = s;
    if (idx < HH) {
        float sb = 0.f;
        for (int j = 0; j < HD; ++j)
            sb = fmaf(bq[idx * HD + j], wm[HD + j], sb);
        qs_bias[idx] = sb;
    }
}

// ---------------- K2/K5: C[M,N] = A[M,K] @ B[K,N] + bias[N]  (fp32 tiled) -------
#define BM 128
#define BN 128
#define BKT 16
__global__ __launch_bounds__(256) void gemm_bias_kernel(
    const float* __restrict__ A, const float* __restrict__ Bm,
    const float* __restrict__ bias, float* __restrict__ C,
    int M, int N, int K)
{
    __shared__ __align__(16) float sA[BKT][BM];   // transposed A tile
    __shared__ __align__(16) float sB[BKT][BN];
    const int tid = threadIdx.x;
    const int tx = tid & 15, ty = tid >> 4;
    const int row0 = blockIdx.y * BM, col0 = blockIdx.x * BN;

    float acc[8][8];
    #pragma unroll
    for (int i = 0; i < 8; ++i)
        #pragma unroll
        for (int j = 0; j < 8; ++j) acc[i][j] = 0.f;

    for (int k0 = 0; k0 < K; k0 += BKT) {
        // A tile: 128 rows x 16 k; 512 float4s, 2 per thread. 4 lanes cover one
        // 64B line per row -> coalesced. Transposed scatter into sA.
        #pragma unroll
        for (int it = 0; it < 2; ++it) {
            int idx = tid + it * 256;
            int r = idx >> 2, c = (idx & 3) << 2;
            float4 v = *(const float4*)(A + (size_t)(row0 + r) * K + k0 + c);
            sA[c + 0][r] = v.x; sA[c + 1][r] = v.y;
            sA[c + 2][r] = v.z; sA[c + 3][r] = v.w;
        }
        // B tile: 16 k x 128 n, straight float4 copy, fully coalesced.
        #pragma unroll
        for (int it = 0; it < 2; ++it) {
            int idx = tid + it * 256;
            int r = idx >> 5, c = (idx & 31) << 2;
            *(float4*)(&sB[r][c]) = *(const float4*)(Bm + (size_t)(k0 + r) * N + col0 + c);
        }
        __syncthreads();
        #pragma unroll
        for (int kk = 0; kk < BKT; ++kk) {
            float a[8], b[8];
            *(float4*)&a[0] = *(const float4*)&sA[kk][ty * 8];
            *(float4*)&a[4] = *(const float4*)&sA[kk][ty * 8 + 4];
            *(float4*)&b[0] = *(const float4*)&sB[kk][tx * 8];
            *(float4*)&b[4] = *(const float4*)&sB[kk][tx * 8 + 4];
            #pragma unroll
            for (int i = 0; i < 8; ++i)
                #pragma unroll
                for (int j = 0; j < 8; ++j)
                    acc[i][j] = fmaf(a[i], b[j], acc[i][j]);
        }
        __syncthreads();
    }
    float bv[8];
    #pragma unroll
    for (int j = 0; j < 8; ++j) bv[j] = bias[col0 + tx * 8 + j];
    #pragma unroll
    for (int i = 0; i < 8; ++i) {
        float* cp = C + (size_t)(row0 + ty * 8 + i) * N + col0 + tx * 8;
        float4 o0, o1;
        o0.x = acc[i][0] + bv[0]; o0.y = acc[i][1] + bv[1];
        o0.z = acc[i][2] + bv[2]; o0.w = acc[i][3] + bv[3];
        o1.x = acc[i][4] + bv[4]; o1.y = acc[i][5] + bv[5];
        o1.z = acc[i][6] + bv[6]; o1.w = acc[i][7] + bv[7];
        *(float4*)cp = o0; *(float4*)(cp + 4) = o1;
    }
}

// ---------------- K3: per-row q_s, k_s ------------------------------------------
__global__ __launch_bounds__(64) void qsks_kernel(
    const float* __restrict__ x, const float* __restrict__ kx,
    const float* __restrict__ vq, const float* __restrict__ qs_bias,
    const float* __restrict__ wm,
    float* __restrict__ qs, float* __restrict__ ks)
{
    int row = blockIdx.x;             // b*T + t
    int lane = threadIdx.x;
    int b = row >> 10, t = row & 1023;
    const float* xr = x + (size_t)row * DD;
    const float* kr = kx + (size_t)row * DD;
    float w1 = wm[lane];              // w_mlp[:64]
    float xv[8];
    #pragma unroll
    for (int i = 0; i < 8; ++i) xv[i] = xr[i * 64 + lane];
    for (int h = 0; h < HH; ++h) {
        float p = 0.f;
        #pragma unroll
        for (int i = 0; i < 8; ++i)
            p = fmaf(xv[i], vq[h * DD + i * 64 + lane], p);
        #pragma unroll
        for (int off = 32; off > 0; off >>= 1) p += __shfl_xor(p, off);
        float pk = kr[h * HD + lane] * w1;   // bk already folded into kx
        #pragma unroll
        for (int off = 32; off > 0; off >>= 1) pk += __shfl_xor(pk, off);
        if (lane == 0) {
            qs[(size_t)(b * HH + h) * TT + t] = p + qs_bias[h];
            ks[(size_t)(b * HH + h) * TT + t] = pk;
        }
    }
}

// ---------------- K4: fused attention -------------------------------------------
// grid (T/64, H, B), block 256 = 4 waves. lane = q within a 64-q chunk.
// wave w accumulates over k in [w*256, (w+1)*256); combined via LDS atomics.
// Weight broadcast uses v_readlane (no LDS traffic per pair).
__global__ __launch_bounds__(256) void attn_kernel(
    const float* __restrict__ kx, const float* __restrict__ qs,
    const float* __restrict__ ks, float* __restrict__ out)
{
    const int qblk = blockIdx.x, h = blockIdx.y, b = blockIdx.z;
    const int tid = threadIdx.x;
    const int lane = tid & 63;
    const int wave = __builtin_amdgcn_readfirstlane(tid >> 6);

    __shared__ float sAcc[64][65];   // [d][q], +1 pad: conflict-free transposed read
    __shared__ float sZ[64];
    for (int i = tid; i < 64 * 65; i += 256) ((float*)sAcc)[i] = 0.f;
    if (tid < 64) sZ[tid] = 0.f;
    __syncthreads();

    const int q0 = qblk * 64;
    const size_t bh = (size_t)(b * HH + h);
    const float qsv = qs[bh * TT + q0 + lane];      // this lane's q-score
    const float* ksp = ks + bh * TT;
    const float* kxp = kx + ((size_t)b * TT) * DD + h * HD;

    float acc[64];
    #pragma unroll
    for (int d = 0; d < 64; ++d) acc[d] = 0.f;
    float Zacc = 0.f;

    const int kbeg = wave * 256, kend = kbeg + 256;
    #pragma unroll 2
    for (int k = kbeg; k < kend; ++k) {
        float ksk = ksp[k];                          // wave-uniform
        float z = qsv + ksk;
        float e2 = __expf(2.f * z);
        float th = __fdividef(e2 - 1.f, e2 + 1.f);   // tanh(z)
        float w = __expf(th);
        Zacc += w;
        float kxv = kxp[(size_t)k * DD + lane];      // kx[k][d=lane], coalesced
        #pragma unroll
        for (int d = 0; d < 64; ++d) {
            float kxs = __uint_as_float(__builtin_amdgcn_readlane(__float_as_uint(kxv), d));
            acc[d] = fmaf(w, kxs, acc[d]);
        }
    }
    #pragma unroll
    for (int d = 0; d < 64; ++d) atomicAdd(&sAcc[d][lane], acc[d]);
    atomicAdd(&sZ[lane], Zacc);
    __syncthreads();

    float* outp = out + ((size_t)b * TT + q0) * DD + h * HD;
    #pragma unroll
    for (int r = 0; r < 16; ++r) {
        int q = r * 4 + (tid >> 6);
        int d = tid & 63;
        outp[(size_t)q * DD + d] = sAcc[d][q] / sZ[q];   // coalesced store
    }
}

// ---------------- K6: residual + LayerNorm --------------------------------------
__global__ __launch_bounds__(256) void ln_kernel(
    const float* __restrict__ x, const float* __restrict__ proj,
    const float* __restrict__ g, const float* __restrict__ bet,
    float* __restrict__ out)
{
    int row = blockIdx.x;
    int tid = threadIdx.x;
    const float* xr = x + (size_t)row * DD;
    const float* pr = proj + (size_t)row * DD;
    float y0 = xr[tid] + pr[tid];
    float y1 = xr[tid + 256] + pr[tid + 256];
    float s = y0 + y1, s2 = y0 * y0 + y1 * y1;
    #pragma unroll
    for (int off = 32; off > 0; off >>= 1) {
        s  += __shfl_xor(s, off);
        s2 += __shfl_xor(s2, off);
    }
    __shared__ float rs[4], rs2[4];
    int wave = tid >> 6, lane = tid & 63;
    if (lane == 0) { rs[wave] = s; rs2[wave] = s2; }
    __syncthreads();
    float S  = rs[0] + rs[1] + rs[2] + rs[3];
    float S2 = rs2[0] + rs2[1] + rs2[2] + rs2[3];
    float mu = S * (1.f / 512.f);
    float var = S2 * (1.f / 512.f) - mu * mu;
    float inv = rsqrtf(var + 1e-5f);
    out[(size_t)row * DD + tid]       = (y0 - mu) * inv * g[tid] + bet[tid];
    out[(size_t)row * DD + tid + 256] = (y1 - mu) * inv * g[tid + 256] + bet[tid + 256];
}

// ---------------- launch --------------------------------------------------------
extern "C" void kernel_launch(void* const* d_in, const int* in_sizes, int n_in,
                              void* d_out, int out_size, void* d_ws, size_t ws_size,
                              hipStream_t stream)
{
    const float* x    = (const float*)d_in[0];
    const float* Wq   = (const float*)d_in[1];
    const float* bq   = (const float*)d_in[2];
    const float* Wk   = (const float*)d_in[3];
    const float* bk   = (const float*)d_in[4];
    const float* Wp   = (const float*)d_in[5];
    const float* bp   = (const float*)d_in[6];
    const float* wm   = (const float*)d_in[7];
    const float* ln_g = (const float*)d_in[8];
    const float* ln_b = (const float*)d_in[9];
    float* out = (float*)d_out;

    float* ws = (float*)d_ws;
    float* vq      = ws;                       // 4096
    float* qs_bias = ws + 4096;                // 8 (pad to 4352)
    float* kx      = ws + 4352;                // 8192*512
    float* qs      = kx + 8192 * 512;          // 65536
    float* ks      = qs + 65536;               // 65536
    float* att     = ks + 65536;               // 8192*512
    float* proj    = kx;                       // kx dead after attention: reuse

    prep_kernel<<<16, 256, 0, stream>>>(Wq, bq, wm, vq, qs_bias);
    gemm_bias_kernel<<<dim3(4, 64), 256, 0, stream>>>(x, Wk, bk, kx, 8192, 512, 512);
    qsks_kernel<<<8192, 64, 0, stream>>>(x, kx, vq, qs_bias, wm, qs, ks);
    attn_kernel<<<dim3(16, 8, 8), 256, 0, stream>>>(kx, qs, ks, att);
    gemm_bias_kernel<<<dim3(4, 64), 256, 0, stream>>>(att, Wp, bp, proj, 8192, 512, 512);
    ln_kernel<<<8192, 256, 0, stream>>>(x, proj, ln_g, ln_b, out);
}

// Round 2
// 210.318 us; speedup vs baseline: 2.4134x; 2.4134x over previous
//
#include <hip/hip_runtime.h>
#include <cstddef>

#define TT 1024
#define DD 512
#define HH 8
#define HD 64

typedef __attribute__((ext_vector_type(8))) short bfrag;   // 8 bf16 (4 VGPRs)
typedef __attribute__((ext_vector_type(4))) float facc;    // 4 fp32 acc

static __device__ __forceinline__ short f2bf(float f) {
    union { float f; unsigned u; } v; v.f = f;
    unsigned r = v.u + 0x7fffu + ((v.u >> 16) & 1u);   // RNE
    return (short)(r >> 16);
}
static __device__ __forceinline__ float bf2f(unsigned short s) {
    union { unsigned u; float f; } v; v.u = ((unsigned)s) << 16;
    return v.f;
}

// ---------------- K1: vq[h][d] = sum_j Wq[d, h*64+j]*w_mlp[64+j]; qs_bias[h] ----
__global__ __launch_bounds__(256) void prep_kernel(
    const float* __restrict__ Wq, const float* __restrict__ bq,
    const float* __restrict__ wm,
    float* __restrict__ vq, float* __restrict__ qs_bias)
{
    int idx = blockIdx.x * 256 + threadIdx.x;   // 0..4095
    int h = idx >> 9, d = idx & 511;
    float s = 0.f;
    #pragma unroll 8
    for (int j = 0; j < HD; ++j)
        s = fmaf(Wq[(size_t)d * DD + h * HD + j], wm[HD + j], s);
    vq[h * DD + d] = s;
    if (idx < HH) {
        float sb = 0.f;
        for (int j = 0; j < HD; ++j)
            sb = fmaf(bq[idx * HD + j], wm[HD + j], sb);
        qs_bias[idx] = sb;
    }
}

// ---------------- bf16 MFMA GEMM: C[M,N] = A[M,K]@B[K,N] + bias ----------------
// 64x64 tile, K-chunk 64. A fp32 or bf16 (template), B fp32, out fp32 or bf16.
// LDS stride 72 bf16 (144B = 36 dwords -> bank step 4 -> 2-way, free per m136).
template<bool A_BF16, bool OUT_BF16>
__global__ __launch_bounds__(256) void mfma_gemm(
    const void* __restrict__ Ap, const float* __restrict__ B,
    const float* __restrict__ bias, void* __restrict__ Cp,
    int M, int N, int K)
{
    __shared__ __align__(16) short sA[64][72];   // [m][k] bf16
    __shared__ __align__(16) short sB[64][72];   // [n][k] bf16 (transposed)
    const int tid = threadIdx.x;
    const int lane = tid & 63;
    const int wave = tid >> 6;
    const int row0 = blockIdx.y * 64, col0 = blockIdx.x * 64;
    const int mhalf = (wave >> 1) * 32, nhalf = (wave & 1) * 32;
    const int l15 = lane & 15, quad = lane >> 4;

    facc acc[2][2] = {{{0.f,0.f,0.f,0.f},{0.f,0.f,0.f,0.f}},
                      {{0.f,0.f,0.f,0.f},{0.f,0.f,0.f,0.f}}};

    for (int k0 = 0; k0 < K; k0 += 64) {
        #pragma unroll
        for (int t = 0; t < 2; ++t) {
            int task = tid + t * 256;
            // A: task -> (m = task>>3, krun = task&7); 8 lanes cover one 256B row run
            int m = task >> 3, kra = task & 7;
            if (A_BF16) {
                const ushort* ap = (const ushort*)Ap + (size_t)(row0 + m) * K + k0 + kra * 8;
                *(uint4*)&sA[m][kra * 8] = *(const uint4*)ap;
            } else {
                const float* ap = (const float*)Ap + (size_t)(row0 + m) * K + k0 + kra * 8;
                float4 v0 = *(const float4*)ap, v1 = *(const float4*)(ap + 4);
                bfrag pk;
                pk[0]=f2bf(v0.x); pk[1]=f2bf(v0.y); pk[2]=f2bf(v0.z); pk[3]=f2bf(v0.w);
                pk[4]=f2bf(v1.x); pk[5]=f2bf(v1.y); pk[6]=f2bf(v1.z); pk[7]=f2bf(v1.w);
                *(bfrag*)&sA[m][kra * 8] = pk;
            }
            // B: task -> (n = task&63, krun = task>>6); lane=n -> 256B coalesced per j
            int n = task & 63, krb = task >> 6;
            const float* bp = B + (size_t)(k0 + krb * 8) * N + col0 + n;
            bfrag pb;
            #pragma unroll
            for (int j = 0; j < 8; ++j) pb[j] = f2bf(bp[(size_t)j * N]);
            *(bfrag*)&sB[n][krb * 8] = pb;
        }
        __syncthreads();
        #pragma unroll
        for (int ks = 0; ks < 2; ++ks) {
            bfrag a0 = *(const bfrag*)&sA[mhalf + l15][ks * 32 + quad * 8];
            bfrag a1 = *(const bfrag*)&sA[mhalf + 16 + l15][ks * 32 + quad * 8];
            bfrag b0 = *(const bfrag*)&sB[nhalf + l15][ks * 32 + quad * 8];
            bfrag b1 = *(const bfrag*)&sB[nhalf + 16 + l15][ks * 32 + quad * 8];
            acc[0][0] = __builtin_amdgcn_mfma_f32_16x16x32_bf16(a0, b0, acc[0][0], 0,0,0);
            acc[0][1] = __builtin_amdgcn_mfma_f32_16x16x32_bf16(a0, b1, acc[0][1], 0,0,0);
            acc[1][0] = __builtin_amdgcn_mfma_f32_16x16x32_bf16(a1, b0, acc[1][0], 0,0,0);
            acc[1][1] = __builtin_amdgcn_mfma_f32_16x16x32_bf16(a1, b1, acc[1][1], 0,0,0);
        }
        __syncthreads();
    }
    // epilogue: C/D layout col=lane&15, row=quad*4+reg (m89-verified)
    #pragma unroll
    for (int mt = 0; mt < 2; ++mt) {
        #pragma unroll
        for (int nt = 0; nt < 2; ++nt) {
            int gcol = col0 + nhalf + nt * 16 + l15;
            float bv = bias[gcol];
            #pragma unroll
            for (int r = 0; r < 4; ++r) {
                int grow = row0 + mhalf + mt * 16 + quad * 4 + r;
                float v = acc[mt][nt][r] + bv;
                if (OUT_BF16)
                    ((ushort*)Cp)[(size_t)grow * N + gcol] = (ushort)f2bf(v);
                else
                    ((float*)Cp)[(size_t)grow * N + gcol] = v;
            }
        }
    }
}

// ---------------- K3: per-row q_s, k_s ------------------------------------------
__global__ __launch_bounds__(256) void qsks_kernel(
    const float* __restrict__ x, const ushort* __restrict__ kxb,
    const float* __restrict__ vq, const float* __restrict__ qs_bias,
    const float* __restrict__ wm,
    float* __restrict__ qs, float* __restrict__ ks)
{
    int tid = threadIdx.x;
    int row = blockIdx.x * 4 + (tid >> 6);    // b*T + t
    int lane = tid & 63;
    int b = row >> 10, t = row & 1023;
    const float* xr = x + (size_t)row * DD;
    const ushort* kr = kxb + (size_t)row * DD;
    float w1 = wm[lane];
    float xv[8];
    #pragma unroll
    for (int i = 0; i < 8; ++i) xv[i] = xr[i * 64 + lane];
    for (int h = 0; h < HH; ++h) {
        float p = 0.f;
        #pragma unroll
        for (int i = 0; i < 8; ++i)
            p = fmaf(xv[i], vq[h * DD + i * 64 + lane], p);
        #pragma unroll
        for (int off = 32; off > 0; off >>= 1) p += __shfl_xor(p, off);
        float pk = bf2f(kr[h * HD + lane]) * w1;
        #pragma unroll
        for (int off = 32; off > 0; off >>= 1) pk += __shfl_xor(pk, off);
        if (lane == 0) {
            qs[(size_t)(b * HH + h) * TT + t] = p + qs_bias[h];
            ks[(size_t)(b * HH + h) * TT + t] = pk;
        }
    }
}

// ---------------- K4: MFMA fused attention --------------------------------------
// grid (16,8,8), block 256 = 4 waves; wave w owns q-subtile [w*16, w*16+16).
// W[q,k]=exp(tanh(qs+ks)) computed IN A-fragment layout (m=lane&15 -> q,
// k=quad*8+j -> ks from LDS) — no LDS round-trip for W. Z via all-ones B-frag.
__global__ __launch_bounds__(256) void attn_kernel(
    const ushort* __restrict__ kxb, const float* __restrict__ qs,
    const float* __restrict__ ks, ushort* __restrict__ attb)
{
    __shared__ __align__(16) short kxT[64][72];   // [d][k] bf16, stride 72
    __shared__ float ksc[64];
    const int qblk = blockIdx.x, h = blockIdx.y, b = blockIdx.z;
    const int tid = threadIdx.x, lane = tid & 63, wave = tid >> 6;
    const int l15 = lane & 15, quad = lane >> 4;
    const int bh = b * HH + h;

    const float qsv = qs[(size_t)bh * TT + qblk * 64 + wave * 16 + l15];
    const float* ksp = ks + (size_t)bh * TT;
    const ushort* kxp = kxb + ((size_t)b * TT) * DD + h * HD;

    facc acc[4] = {{0.f,0.f,0.f,0.f},{0.f,0.f,0.f,0.f},
                   {0.f,0.f,0.f,0.f},{0.f,0.f,0.f,0.f}};
    facc accZ = {0.f,0.f,0.f,0.f};
    bfrag ones;
    #pragma unroll
    for (int j = 0; j < 8; ++j) ones[j] = (short)0x3F80;   // bf16 1.0

    for (int ck = 0; ck < 16; ++ck) {
        const int k0 = ck * 64;
        // stage kx chunk transposed: [d][k] bf16
        #pragma unroll
        for (int t = 0; t < 2; ++t) {
            int task = tid + t * 256;
            int d = task & 63, kr = task >> 6;
            const ushort* p = kxp + (size_t)(k0 + kr * 8) * DD + d;
            bfrag pk;
            #pragma unroll
            for (int j = 0; j < 8; ++j) pk[j] = (short)p[(size_t)j * DD];
            *(bfrag*)&kxT[d][kr * 8] = pk;
        }
        if (tid < 64) ksc[tid] = ksp[k0 + tid];
        __syncthreads();
        #pragma unroll
        for (int ks_ = 0; ks_ < 2; ++ks_) {
            const float* kvp = &ksc[ks_ * 32 + quad * 8];
            float4 kv0 = *(const float4*)kvp;        // same-quad lanes: broadcast, free
            float4 kv1 = *(const float4*)(kvp + 4);
            float zk[8] = {kv0.x, kv0.y, kv0.z, kv0.w, kv1.x, kv1.y, kv1.z, kv1.w};
            bfrag af;
            #pragma unroll
            for (int j = 0; j < 8; ++j) {
                float z = qsv + zk[j];
                float e2 = __expf(2.f * z);
                float th = __fdividef(e2 - 1.f, e2 + 1.f);   // tanh(z)
                af[j] = f2bf(__expf(th));
            }
            #pragma unroll
            for (int dt = 0; dt < 4; ++dt) {
                bfrag bf_ = *(const bfrag*)&kxT[dt * 16 + l15][ks_ * 32 + quad * 8];
                acc[dt] = __builtin_amdgcn_mfma_f32_16x16x32_bf16(af, bf_, acc[dt], 0,0,0);
            }
            accZ = __builtin_amdgcn_mfma_f32_16x16x32_bf16(af, ones, accZ, 0,0,0);
        }
        __syncthreads();
    }
    // epilogue: out = acc/Z; Z[row] lines up with acc reg index (same C-row)
    const size_t rowbase = (size_t)b * TT + qblk * 64 + wave * 16;
    #pragma unroll
    for (int r = 0; r < 4; ++r) {
        int q = quad * 4 + r;
        float inv = 1.f / accZ[r];
        size_t off = (rowbase + q) * DD + h * HD + l15;
        #pragma unroll
        for (int dt = 0; dt < 4; ++dt)
            attb[off + dt * 16] = (ushort)f2bf(acc[dt][r] * inv);
    }
}

// ---------------- K6: residual + LayerNorm --------------------------------------
__global__ __launch_bounds__(256) void ln_kernel(
    const float* __restrict__ x, const float* __restrict__ proj,
    const float* __restrict__ g, const float* __restrict__ bet,
    float* __restrict__ out)
{
    int row = blockIdx.x;
    int tid = threadIdx.x;
    const float* xr = x + (size_t)row * DD;
    const float* pr = proj + (size_t)row * DD;
    float y0 = xr[tid] + pr[tid];
    float y1 = xr[tid + 256] + pr[tid + 256];
    float s = y0 + y1, s2 = y0 * y0 + y1 * y1;
    #pragma unroll
    for (int off = 32; off > 0; off >>= 1) {
        s  += __shfl_xor(s, off);
        s2 += __shfl_xor(s2, off);
    }
    __shared__ float rs[4], rs2[4];
    int wave = tid >> 6, lane = tid & 63;
    if (lane == 0) { rs[wave] = s; rs2[wave] = s2; }
    __syncthreads();
    float S  = rs[0] + rs[1] + rs[2] + rs[3];
    float S2 = rs2[0] + rs2[1] + rs2[2] + rs2[3];
    float mu = S * (1.f / 512.f);
    float var = S2 * (1.f / 512.f) - mu * mu;
    float inv = rsqrtf(var + 1e-5f);
    out[(size_t)row * DD + tid]       = (y0 - mu) * inv * g[tid] + bet[tid];
    out[(size_t)row * DD + tid + 256] = (y1 - mu) * inv * g[tid + 256] + bet[tid + 256];
}

// ---------------- launch --------------------------------------------------------
extern "C" void kernel_launch(void* const* d_in, const int* in_sizes, int n_in,
                              void* d_out, int out_size, void* d_ws, size_t ws_size,
                              hipStream_t stream)
{
    const float* x    = (const float*)d_in[0];
    const float* Wq   = (const float*)d_in[1];
    const float* bq   = (const float*)d_in[2];
    const float* Wk   = (const float*)d_in[3];
    const float* bk   = (const float*)d_in[4];
    const float* Wp   = (const float*)d_in[5];
    const float* bp   = (const float*)d_in[6];
    const float* wm   = (const float*)d_in[7];
    const float* ln_g = (const float*)d_in[8];
    const float* ln_b = (const float*)d_in[9];
    float* out = (float*)d_out;

    float* ws = (float*)d_ws;
    float*  vq      = ws;                                  // 4096
    float*  qs_bias = ws + 4096;                           // 8 (pad to 4352)
    ushort* kxb     = (ushort*)(ws + 4352);                // 8192*512 bf16 = 2097152 f
    float*  qs      = ws + 4352 + 2097152;                 // 65536
    float*  ks      = qs + 65536;                          // 65536
    ushort* attb    = (ushort*)(ks + 65536);               // 8192*512 bf16 = 2097152 f
    float*  proj    = ks + 65536 + 2097152;                // 8192*512 fp32

    prep_kernel<<<16, 256, 0, stream>>>(Wq, bq, wm, vq, qs_bias);
    mfma_gemm<false, true><<<dim3(8, 128), 256, 0, stream>>>(x, Wk, bk, kxb, 8192, 512, 512);
    qsks_kernel<<<2048, 256, 0, stream>>>(x, kxb, vq, qs_bias, wm, qs, ks);
    attn_kernel<<<dim3(16, 8, 8), 256, 0, stream>>>(kxb, qs, ks, attb);
    mfma_gemm<true, false><<<dim3(8, 128), 256, 0, stream>>>(attb, Wp, bp, proj, 8192, 512, 512);
    ln_kernel<<<8192, 256, 0, stream>>>(x, proj, ln_g, ln_b, out);
}

// Round 3
// 162.673 us; speedup vs baseline: 3.1202x; 1.2929x over previous
//
#include <hip/hip_runtime.h>
#include <cstddef>

#define TT 1024
#define DDIM 512
#define HH 8

typedef __attribute__((ext_vector_type(8))) short bfrag;   // 8 bf16 (4 VGPRs)
typedef __attribute__((ext_vector_type(4))) float facc;    // 4 fp32 acc

#define SC2   2.8853900817779268f   // 2*log2(e)
#define L2E   1.4426950408889634f

static __device__ __forceinline__ unsigned bfrne(float f) {
    unsigned u = __float_as_uint(f);
    return (u + 0x7fffu + ((u >> 16) & 1u)) >> 16;
}
static __device__ __forceinline__ unsigned pack2rne(float a, float b) {
    return bfrne(a) | (bfrne(b) << 16);
}
// half-up pack (hot path, weights only)
static __device__ __forceinline__ unsigned pack2hu(float a, float b) {
    return ((__float_as_uint(a) + 0x8000u) >> 16) |
           ((__float_as_uint(b) + 0x8000u) & 0xffff0000u);
}
// async 16B global->LDS (linear dest: wave-uniform base + lane*16)
static __device__ __forceinline__ void gl2lds16(const void* g, void* l) {
    __builtin_amdgcn_global_load_lds(
        (const __attribute__((address_space(1))) unsigned int*)g,
        (__attribute__((address_space(3))) unsigned int*)l, 16, 0, 0);
}
// w(z2) = exp(tanh(z)) with z2 = 2*log2e*z pre-scaled: 3 trans + 2 VALU
static __device__ __forceinline__ float wfun(float z2) {
    float t = __builtin_amdgcn_exp2f(z2);
    float r = __builtin_amdgcn_rcpf(t + 1.f);
    return __builtin_amdgcn_exp2f(fmaf(r, -2.f * L2E, L2E));
}

// ---- K1: vq2[h][d] = (sum_j Wq[d][h*64+j]*wm[64+j])*SC2 ; qsb2[h] -------------
__global__ __launch_bounds__(256) void prep_kernel(
    const float* __restrict__ Wq, const float* __restrict__ bq,
    const float* __restrict__ wm,
    float* __restrict__ vq2, float* __restrict__ qsb2)
{
    int idx = blockIdx.x * 256 + threadIdx.x;   // 0..4095
    int h = idx >> 9, d = idx & 511;
    float s = 0.f;
    #pragma unroll 8
    for (int j = 0; j < 64; ++j)
        s = fmaf(Wq[(size_t)d * DDIM + h * 64 + j], wm[64 + j], s);
    vq2[h * DDIM + d] = s * SC2;
    if (idx < HH) {
        float sb = 0.f;
        for (int j = 0; j < 64; ++j)
            sb = fmaf(bq[idx * 64 + j], wm[64 + j], sb);
        qsb2[idx] = sb * SC2;
    }
}

// ---- K2: transpose Wk/Wp -> [n][k] bf16, granule-swizzled ---------------------
__global__ __launch_bounds__(256) void trans_kernel(
    const float* __restrict__ Wk, const float* __restrict__ Wp,
    unsigned short* __restrict__ WkT, unsigned short* __restrict__ WpT)
{
    const float* src = blockIdx.z ? Wp : Wk;
    unsigned short* dst = blockIdx.z ? WpT : WkT;
    const int n0 = blockIdx.x * 64, k0 = blockIdx.y * 64;
    __shared__ float sT[64][65];
    const int tid = threadIdx.x;
    #pragma unroll
    for (int it = 0; it < 4; ++it) {
        int task = it * 256 + tid;
        int kr = task >> 4, c4 = (task & 15) * 4;
        float4 v = *(const float4*)(src + (size_t)(k0 + kr) * DDIM + n0 + c4);
        sT[kr][c4] = v.x; sT[kr][c4 + 1] = v.y; sT[kr][c4 + 2] = v.z; sT[kr][c4 + 3] = v.w;
    }
    __syncthreads();
    #pragma unroll
    for (int it = 0; it < 2; ++it) {
        int task = it * 256 + tid;
        int n = task >> 3, kg = task & 7;
        unsigned u[4];
        #pragma unroll
        for (int jj = 0; jj < 4; ++jj)
            u[jj] = pack2rne(sT[kg * 8 + jj * 2][n], sT[kg * 8 + jj * 2 + 1][n]);
        int p = ((k0 >> 3) + kg) ^ (n & 7);
        uint4 st; st.x = u[0]; st.y = u[1]; st.z = u[2]; st.w = u[3];
        *(uint4*)(dst + (size_t)(n0 + n) * DDIM + p * 8) = st;
    }
}

// ---- K3: x -> xb (bf16 swizzled) + qs2 (pre-scaled, bias folded) --------------
__global__ __launch_bounds__(256) void preconv_kernel(
    const float* __restrict__ x, const float* __restrict__ vq2,
    const float* __restrict__ qsb2,
    unsigned short* __restrict__ xb, float* __restrict__ qs2)
{
    const int tid = threadIdx.x, lane = tid & 63, wave = tid >> 6;
    const int row = blockIdx.x * 4 + wave;
    const float* xr = x + (size_t)row * DDIM;
    float4 x0 = ((const float4*)xr)[lane * 2];
    float4 x1 = ((const float4*)xr)[lane * 2 + 1];
    float xv[8] = {x0.x, x0.y, x0.z, x0.w, x1.x, x1.y, x1.z, x1.w};
    uint4 st;
    st.x = pack2rne(xv[0], xv[1]); st.y = pack2rne(xv[2], xv[3]);
    st.z = pack2rne(xv[4], xv[5]); st.w = pack2rne(xv[6], xv[7]);
    int p = lane ^ (row & 7);
    *(uint4*)(xb + (size_t)row * DDIM + p * 8) = st;
    const int b = row >> 10, t = row & 1023;
    for (int h = 0; h < HH; ++h) {
        const float* vp = vq2 + h * DDIM + lane * 8;
        float4 v0 = *(const float4*)vp, v1 = *(const float4*)(vp + 4);
        float s = xv[0] * v0.x;
        s = fmaf(xv[1], v0.y, s); s = fmaf(xv[2], v0.z, s); s = fmaf(xv[3], v0.w, s);
        s = fmaf(xv[4], v1.x, s); s = fmaf(xv[5], v1.y, s);
        s = fmaf(xv[6], v1.z, s); s = fmaf(xv[7], v1.w, s);
        #pragma unroll
        for (int off = 32; off > 0; off >>= 1) s += __shfl_xor(s, off);
        if (lane == 0) qs2[(size_t)(b * HH + h) * TT + t] = s + qsb2[h];
    }
}

// ---- GEMM template: 128x128 tile, BK=64, pure global_load_lds staging ---------
// A[m][K], B[n][K] both bf16, granule-swizzled. EPI 0: fp32 C+bias. EPI 1:
// transposed-swizzled bf16 kxT_g[b,h,d,t] + bias, plus ks2 (pre-scaled).
template<int EPI>
__global__ __launch_bounds__(256) void gemm_kernel(
    const unsigned short* __restrict__ A, const unsigned short* __restrict__ B,
    const float* __restrict__ bias, float* __restrict__ Cf,
    unsigned short* __restrict__ kxTg, float* __restrict__ ks2,
    const float* __restrict__ wm)
{
    const int K = 512, N = 512;
    __shared__ __align__(16) unsigned short sA[128 * 64];
    __shared__ __align__(16) unsigned short sB[128 * 64];
    const int tid = threadIdx.x, lane = tid & 63, wave = tid >> 6;
    const int l15 = lane & 15, quad = lane >> 4;
    const int wr = wave >> 1, wc = wave & 1;
    const int row0 = blockIdx.y * 128, col0 = blockIdx.x * 128;

    facc acc[4][4];
    #pragma unroll
    for (int i = 0; i < 4; ++i)
        #pragma unroll
        for (int j = 0; j < 4; ++j) { acc[i][j][0]=0.f; acc[i][j][1]=0.f; acc[i][j][2]=0.f; acc[i][j][3]=0.f; }

    for (int k0 = 0; k0 < K; k0 += 64) {
        #pragma unroll
        for (int it = 0; it < 4; ++it) {
            int g = it * 256 + tid;
            int r = g >> 3, kg = g & 7;
            gl2lds16(A + (size_t)(row0 + r) * K + k0 + kg * 8, &sA[g * 8]);
            gl2lds16(B + (size_t)(col0 + r) * K + k0 + kg * 8, &sB[g * 8]);
        }
        __syncthreads();
        #pragma unroll
        for (int ks_ = 0; ks_ < 2; ++ks_) {
            bfrag a[4], b[4];
            int slot = (ks_ * 4 + quad) ^ (l15 & 7);
            #pragma unroll
            for (int i = 0; i < 4; ++i) {
                a[i] = *(const bfrag*)&sA[(wr * 64 + i * 16 + l15) * 64 + slot * 8];
                b[i] = *(const bfrag*)&sB[(wc * 64 + i * 16 + l15) * 64 + slot * 8];
            }
            #pragma unroll
            for (int mt = 0; mt < 4; ++mt)
                #pragma unroll
                for (int nt = 0; nt < 4; ++nt)
                    acc[mt][nt] = __builtin_amdgcn_mfma_f32_16x16x32_bf16(a[mt], b[nt], acc[mt][nt], 0, 0, 0);
        }
        __syncthreads();
    }

    if (EPI == 0) {
        #pragma unroll
        for (int mt = 0; mt < 4; ++mt) {
            int grow = row0 + wr * 64 + mt * 16 + quad * 4;
            #pragma unroll
            for (int nt = 0; nt < 4; ++nt) {
                int col = col0 + wc * 64 + nt * 16 + l15;
                float bv = bias[col];
                #pragma unroll
                for (int r = 0; r < 4; ++r)
                    Cf[(size_t)(grow + r) * N + col] = acc[mt][nt][r] + bv;
            }
        }
    } else {
        float part[4][4];
        #pragma unroll
        for (int i = 0; i < 4; ++i)
            #pragma unroll
            for (int r = 0; r < 4; ++r) part[i][r] = 0.f;
        float wmv[4];
        #pragma unroll
        for (int nt = 0; nt < 4; ++nt) wmv[nt] = wm[nt * 16 + l15] * SC2;
        const int h = blockIdx.x * 2 + wc;
        #pragma unroll
        for (int mt = 0; mt < 4; ++mt) {
            int grow = row0 + wr * 64 + mt * 16 + quad * 4;
            int bb = grow >> 10, t0 = grow & 1023;
            int gt = t0 >> 3, half = t0 & 7;   // half in {0,4}
            #pragma unroll
            for (int nt = 0; nt < 4; ++nt) {
                int col = col0 + wc * 64 + nt * 16 + l15;
                int d = col & 63;
                float bv = bias[col];
                float v0 = acc[mt][nt][0] + bv, v1 = acc[mt][nt][1] + bv;
                float v2 = acc[mt][nt][2] + bv, v3 = acc[mt][nt][3] + bv;
                part[mt][0] = fmaf(wmv[nt], v0, part[mt][0]);
                part[mt][1] = fmaf(wmv[nt], v1, part[mt][1]);
                part[mt][2] = fmaf(wmv[nt], v2, part[mt][2]);
                part[mt][3] = fmaf(wmv[nt], v3, part[mt][3]);
                unsigned short* rp = kxTg + ((size_t)(bb * HH + h) * 64 + d) * TT;
                int p = gt ^ (d & 7);
                uint2 st; st.x = pack2rne(v0, v1); st.y = pack2rne(v2, v3);
                *(uint2*)(rp + p * 8 + half) = st;
            }
        }
        #pragma unroll
        for (int mt = 0; mt < 4; ++mt)
            #pragma unroll
            for (int r = 0; r < 4; ++r) {
                float p = part[mt][r];
                p += __shfl_xor(p, 1); p += __shfl_xor(p, 2);
                p += __shfl_xor(p, 4); p += __shfl_xor(p, 8);
                part[mt][r] = p;
            }
        if (l15 == 0) {
            #pragma unroll
            for (int mt = 0; mt < 4; ++mt) {
                int grow = row0 + wr * 64 + mt * 16 + quad * 4;
                int bb = grow >> 10;
                #pragma unroll
                for (int r = 0; r < 4; ++r)
                    ks2[(size_t)(bb * HH + h) * TT + ((grow + r) & 1023)] = part[mt][r];
            }
        }
    }
}

// ---- K5: MFMA fused attention -------------------------------------------------
// grid (16,8,8), 256 thr. kxT_g staged linearly via global_load_lds (swizzle
// preserved); weights built directly in A-frag layout; Z via all-ones B-frag.
__global__ __launch_bounds__(256) void attn_kernel(
    const unsigned short* __restrict__ kxTg, const float* __restrict__ qs2,
    const float* __restrict__ ks2, unsigned short* __restrict__ attb)
{
    __shared__ __align__(16) unsigned short kxT[64 * 256];  // 32 KB
    __shared__ __align__(16) float ksc[1024];               // 4 KB
    const int qblk = blockIdx.x, h = blockIdx.y, b = blockIdx.z;
    const int tid = threadIdx.x, lane = tid & 63, wave = tid >> 6;
    const int l15 = lane & 15, quad = lane >> 4;
    const int bh = b * HH + h;

    ((float4*)ksc)[tid] = ((const float4*)(ks2 + (size_t)bh * TT))[tid];
    const float qsv = qs2[(size_t)bh * TT + qblk * 64 + wave * 16 + l15];
    const unsigned short* kxbase = kxTg + (size_t)bh * 64 * TT;

    facc acc[4]; facc accZ;
    #pragma unroll
    for (int i = 0; i < 4; ++i) { acc[i][0]=0.f; acc[i][1]=0.f; acc[i][2]=0.f; acc[i][3]=0.f; }
    accZ[0]=0.f; accZ[1]=0.f; accZ[2]=0.f; accZ[3]=0.f;
    bfrag ones;
    #pragma unroll
    for (int j = 0; j < 8; ++j) ones[j] = (short)0x3F80;

    for (int ck = 0; ck < 4; ++ck) {
        #pragma unroll
        for (int it = 0; it < 8; ++it) {
            int g = it * 256 + tid;
            int d = g >> 5, j = g & 31;
            gl2lds16(kxbase + (size_t)d * TT + ck * 256 + j * 8, &kxT[g * 8]);
        }
        __syncthreads();
        #pragma unroll
        for (int kst = 0; kst < 8; ++kst) {
            const float* kvp = &ksc[ck * 256 + kst * 32 + quad * 8];
            float4 kv0 = *(const float4*)kvp;        // quad-uniform: LDS broadcast
            float4 kv1 = *(const float4*)(kvp + 4);
            union { unsigned u[4]; bfrag f; } afu;
            afu.u[0] = pack2hu(wfun(qsv + kv0.x), wfun(qsv + kv0.y));
            afu.u[1] = pack2hu(wfun(qsv + kv0.z), wfun(qsv + kv0.w));
            afu.u[2] = pack2hu(wfun(qsv + kv1.x), wfun(qsv + kv1.y));
            afu.u[3] = pack2hu(wfun(qsv + kv1.z), wfun(qsv + kv1.w));
            bfrag af = afu.f;
            int slot = (kst * 4 + quad) ^ (l15 & 7);
            #pragma unroll
            for (int dt = 0; dt < 4; ++dt) {
                bfrag bf_ = *(const bfrag*)&kxT[(dt * 16 + l15) * 256 + slot * 8];
                acc[dt] = __builtin_amdgcn_mfma_f32_16x16x32_bf16(af, bf_, acc[dt], 0, 0, 0);
            }
            accZ = __builtin_amdgcn_mfma_f32_16x16x32_bf16(af, ones, accZ, 0, 0, 0);
        }
        __syncthreads();
    }
    // epilogue: attb[row][col] bf16, granule-swizzled (GEMM2 A-operand format)
    #pragma unroll
    for (int r = 0; r < 4; ++r) {
        float inv = __builtin_amdgcn_rcpf(accZ[r]);
        int trow = qblk * 64 + wave * 16 + quad * 4 + r;
        int grow = b * TT + trow;
        unsigned short* rp = attb + (size_t)grow * DDIM;
        int s = trow & 7;
        #pragma unroll
        for (int dt = 0; dt < 4; ++dt) {
            int col = h * 64 + dt * 16 + l15;
            int p = (col >> 3) ^ s;
            rp[p * 8 + (col & 7)] = (unsigned short)bfrne(acc[dt][r] * inv);
        }
    }
}

// ---- K7: residual + LayerNorm (wave per row, float4) --------------------------
__global__ __launch_bounds__(256) void ln_kernel(
    const float* __restrict__ x, const float* __restrict__ proj,
    const float* __restrict__ g, const float* __restrict__ bet,
    float* __restrict__ out)
{
    const int tid = threadIdx.x, lane = tid & 63, wave = tid >> 6;
    const int row = blockIdx.x * 4 + wave;
    const float4* xr = (const float4*)(x + (size_t)row * DDIM);
    const float4* pr = (const float4*)(proj + (size_t)row * DDIM);
    float4 a0 = xr[lane * 2], a1 = xr[lane * 2 + 1];
    float4 p0 = pr[lane * 2], p1 = pr[lane * 2 + 1];
    float y[8] = {a0.x + p0.x, a0.y + p0.y, a0.z + p0.z, a0.w + p0.w,
                  a1.x + p1.x, a1.y + p1.y, a1.z + p1.z, a1.w + p1.w};
    float s = 0.f, s2 = 0.f;
    #pragma unroll
    for (int i = 0; i < 8; ++i) { s += y[i]; s2 = fmaf(y[i], y[i], s2); }
    #pragma unroll
    for (int off = 32; off > 0; off >>= 1) {
        s += __shfl_xor(s, off);
        s2 += __shfl_xor(s2, off);
    }
    float mu = s * (1.f / 512.f);
    float var = s2 * (1.f / 512.f) - mu * mu;
    float inv = rsqrtf(var + 1e-5f);
    const float4* gp = (const float4*)(g + lane * 8);
    const float4* bp = (const float4*)(bet + lane * 8);
    float4 g0 = gp[0], g1 = gp[1], b0 = bp[0], b1 = bp[1];
    float4 o0, o1;
    o0.x = (y[0] - mu) * inv * g0.x + b0.x; o0.y = (y[1] - mu) * inv * g0.y + b0.y;
    o0.z = (y[2] - mu) * inv * g0.z + b0.z; o0.w = (y[3] - mu) * inv * g0.w + b0.w;
    o1.x = (y[4] - mu) * inv * g1.x + b1.x; o1.y = (y[5] - mu) * inv * g1.y + b1.y;
    o1.z = (y[6] - mu) * inv * g1.z + b1.z; o1.w = (y[7] - mu) * inv * g1.w + b1.w;
    float4* op = (float4*)(out + (size_t)row * DDIM);
    op[lane * 2] = o0; op[lane * 2 + 1] = o1;
}

// ---- launch -------------------------------------------------------------------
extern "C" void kernel_launch(void* const* d_in, const int* in_sizes, int n_in,
                              void* d_out, int out_size, void* d_ws, size_t ws_size,
                              hipStream_t stream)
{
    const float* x    = (const float*)d_in[0];
    const float* Wq   = (const float*)d_in[1];
    const float* bq   = (const float*)d_in[2];
    const float* Wk   = (const float*)d_in[3];
    const float* bk   = (const float*)d_in[4];
    const float* Wp   = (const float*)d_in[5];
    const float* bp   = (const float*)d_in[6];
    const float* wm   = (const float*)d_in[7];
    const float* ln_g = (const float*)d_in[8];
    const float* ln_b = (const float*)d_in[9];
    float* out = (float*)d_out;

    float* ws = (float*)d_ws;
    float*          vq2  = ws;                                   // 4096
    float*          qsb2 = ws + 4096;                            // 8
    unsigned short* WkT  = (unsigned short*)(ws + 4352);         // 131072 f
    unsigned short* WpT  = (unsigned short*)(ws + 135424);       // 131072 f
    unsigned short* xb   = (unsigned short*)(ws + 266496);       // 2097152 f
    unsigned short* kxTg = (unsigned short*)(ws + 2363648);      // 2097152 f
    float*          qs2  = ws + 4460800;                         // 65536
    float*          ks2  = ws + 4526336;                         // 65536
    unsigned short* attb = (unsigned short*)(ws + 4591872);      // 2097152 f
    float*          proj = ws + 266496;  // aliases xb+kxTg (both dead by GEMM2)

    prep_kernel<<<16, 256, 0, stream>>>(Wq, bq, wm, vq2, qsb2);
    trans_kernel<<<dim3(8, 8, 2), 256, 0, stream>>>(Wk, Wp, WkT, WpT);
    preconv_kernel<<<2048, 256, 0, stream>>>(x, vq2, qsb2, xb, qs2);
    gemm_kernel<1><<<dim3(4, 64), 256, 0, stream>>>(xb, WkT, bk, nullptr, kxTg, ks2, wm);
    attn_kernel<<<dim3(16, 8, 8), 256, 0, stream>>>(kxTg, qs2, ks2, attb);
    gemm_kernel<0><<<dim3(4, 64), 256, 0, stream>>>(attb, WpT, bp, proj, nullptr, nullptr, nullptr);
    ln_kernel<<<2048, 256, 0, stream>>>(x, proj, ln_g, ln_b, out);
}

// Round 4
// 158.663 us; speedup vs baseline: 3.1991x; 1.0253x over previous
//
#include <hip/hip_runtime.h>
#include <cstddef>

#define TT 1024
#define DDIM 512
#define HH 8
#define NND 128          // interpolation nodes per (b,h)
#define NW 72            // node_out row width: 64 d + Z at [64], padded

typedef __attribute__((ext_vector_type(8))) short bfrag;   // 8 bf16 (4 VGPRs)
typedef __attribute__((ext_vector_type(4))) float facc;    // 4 fp32 acc

#define SC2   2.8853900817779268f   // 2*log2(e)
#define L2E   1.4426950408889634f

static __device__ __forceinline__ unsigned bfrne(float f) {
    unsigned u = __float_as_uint(f);
    return (u + 0x7fffu + ((u >> 16) & 1u)) >> 16;
}
static __device__ __forceinline__ unsigned pack2rne(float a, float b) {
    return bfrne(a) | (bfrne(b) << 16);
}
static __device__ __forceinline__ unsigned pack2hu(float a, float b) {
    return ((__float_as_uint(a) + 0x8000u) >> 16) |
           ((__float_as_uint(b) + 0x8000u) & 0xffff0000u);
}
static __device__ __forceinline__ void gl2lds16(const void* g, void* l) {
    __builtin_amdgcn_global_load_lds(
        (const __attribute__((address_space(1))) unsigned int*)g,
        (__attribute__((address_space(3))) unsigned int*)l, 16, 0, 0);
}
// w(z2) = exp(tanh(z)) with z2 = 2*log2e*z pre-scaled
static __device__ __forceinline__ float wfun(float z2) {
    float t = __builtin_amdgcn_exp2f(z2);
    float r = __builtin_amdgcn_rcpf(t + 1.f);
    return __builtin_amdgcn_exp2f(fmaf(r, -2.f * L2E, L2E));
}

// ---- K1: vq2[h][d] = (sum_j Wq[d][h*64+j]*wm[64+j])*SC2 ; qsb2[h] -------------
__global__ __launch_bounds__(256) void prep_kernel(
    const float* __restrict__ Wq, const float* __restrict__ bq,
    const float* __restrict__ wm,
    float* __restrict__ vq2, float* __restrict__ qsb2)
{
    int idx = blockIdx.x * 256 + threadIdx.x;   // 0..4095
    int h = idx >> 9, d = idx & 511;
    float s = 0.f;
    #pragma unroll 8
    for (int j = 0; j < 64; ++j)
        s = fmaf(Wq[(size_t)d * DDIM + h * 64 + j], wm[64 + j], s);
    vq2[h * DDIM + d] = s * SC2;
    if (idx < HH) {
        float sb = 0.f;
        for (int j = 0; j < 64; ++j)
            sb = fmaf(bq[idx * 64 + j], wm[64 + j], sb);
        qsb2[idx] = sb * SC2;
    }
}

// ---- K2: transpose Wk/Wp -> [n][k] bf16, granule-swizzled ---------------------
__global__ __launch_bounds__(256) void trans_kernel(
    const float* __restrict__ Wk, const float* __restrict__ Wp,
    unsigned short* __restrict__ WkT, unsigned short* __restrict__ WpT)
{
    const float* src = blockIdx.z ? Wp : Wk;
    unsigned short* dst = blockIdx.z ? WpT : WkT;
    const int n0 = blockIdx.x * 64, k0 = blockIdx.y * 64;
    __shared__ float sT[64][65];
    const int tid = threadIdx.x;
    #pragma unroll
    for (int it = 0; it < 4; ++it) {
        int task = it * 256 + tid;
        int kr = task >> 4, c4 = (task & 15) * 4;
        float4 v = *(const float4*)(src + (size_t)(k0 + kr) * DDIM + n0 + c4);
        sT[kr][c4] = v.x; sT[kr][c4 + 1] = v.y; sT[kr][c4 + 2] = v.z; sT[kr][c4 + 3] = v.w;
    }
    __syncthreads();
    #pragma unroll
    for (int it = 0; it < 2; ++it) {
        int task = it * 256 + tid;
        int n = task >> 3, kg = task & 7;
        unsigned u[4];
        #pragma unroll
        for (int jj = 0; jj < 4; ++jj)
            u[jj] = pack2rne(sT[kg * 8 + jj * 2][n], sT[kg * 8 + jj * 2 + 1][n]);
        int p = ((k0 >> 3) + kg) ^ (n & 7);
        uint4 st; st.x = u[0]; st.y = u[1]; st.z = u[2]; st.w = u[3];
        *(uint4*)(dst + (size_t)(n0 + n) * DDIM + p * 8) = st;
    }
}

// ---- K3: x -> xb (bf16 swizzled) + qs2 (pre-scaled, bias folded) --------------
__global__ __launch_bounds__(256) void preconv_kernel(
    const float* __restrict__ x, const float* __restrict__ vq2,
    const float* __restrict__ qsb2,
    unsigned short* __restrict__ xb, float* __restrict__ qs2)
{
    const int tid = threadIdx.x, lane = tid & 63, wave = tid >> 6;
    const int row = blockIdx.x * 4 + wave;
    const float* xr = x + (size_t)row * DDIM;
    float4 x0 = ((const float4*)xr)[lane * 2];
    float4 x1 = ((const float4*)xr)[lane * 2 + 1];
    float xv[8] = {x0.x, x0.y, x0.z, x0.w, x1.x, x1.y, x1.z, x1.w};
    uint4 st;
    st.x = pack2rne(xv[0], xv[1]); st.y = pack2rne(xv[2], xv[3]);
    st.z = pack2rne(xv[4], xv[5]); st.w = pack2rne(xv[6], xv[7]);
    int p = lane ^ (row & 7);
    *(uint4*)(xb + (size_t)row * DDIM + p * 8) = st;
    const int b = row >> 10, t = row & 1023;
    for (int h = 0; h < HH; ++h) {
        const float* vp = vq2 + h * DDIM + lane * 8;
        float4 v0 = *(const float4*)vp, v1 = *(const float4*)(vp + 4);
        float s = xv[0] * v0.x;
        s = fmaf(xv[1], v0.y, s); s = fmaf(xv[2], v0.z, s); s = fmaf(xv[3], v0.w, s);
        s = fmaf(xv[4], v1.x, s); s = fmaf(xv[5], v1.y, s);
        s = fmaf(xv[6], v1.z, s); s = fmaf(xv[7], v1.w, s);
        #pragma unroll
        for (int off = 32; off > 0; off >>= 1) s += __shfl_xor(s, off);
        if (lane == 0) qs2[(size_t)(b * HH + h) * TT + t] = s + qsb2[h];
    }
}

// ---- K4: GEMM1 kx = xb @ WkT + bk. Tile 128 t x 64 d (one head), BK=64. -------
// Epilogue: LDS transpose -> coalesced swizzled kxTg[bh][d][t] bf16, + ks2.
__global__ __launch_bounds__(256) void gemm1_kernel(
    const unsigned short* __restrict__ A, const unsigned short* __restrict__ B,
    const float* __restrict__ bias, unsigned short* __restrict__ kxTg,
    float* __restrict__ ks2, const float* __restrict__ wm)
{
    __shared__ __align__(16) unsigned short smem[12288];   // sA 8192 | sB 4096; epi 8448
    unsigned short* sA = smem;
    unsigned short* sB = smem + 8192;
    const int tid = threadIdx.x, lane = tid & 63, wave = tid >> 6;
    const int l15 = lane & 15, quad = lane >> 4;
    const int h = blockIdx.x, row0 = blockIdx.y * 128;
    const int col0 = h * 64;

    facc acc[2][4];
    #pragma unroll
    for (int i = 0; i < 2; ++i)
        #pragma unroll
        for (int j = 0; j < 4; ++j) { acc[i][j][0]=0.f; acc[i][j][1]=0.f; acc[i][j][2]=0.f; acc[i][j][3]=0.f; }

    for (int k0 = 0; k0 < 512; k0 += 64) {
        #pragma unroll
        for (int it = 0; it < 4; ++it) {
            int g = it * 256 + tid;
            int r = g >> 3, kg = g & 7;
            gl2lds16(A + (size_t)(row0 + r) * 512 + k0 + kg * 8, &sA[g * 8]);
        }
        #pragma unroll
        for (int it = 0; it < 2; ++it) {
            int g = it * 256 + tid;
            int r = g >> 3, kg = g & 7;
            gl2lds16(B + (size_t)(col0 + r) * 512 + k0 + kg * 8, &sB[g * 8]);
        }
        __syncthreads();
        #pragma unroll
        for (int ks_ = 0; ks_ < 2; ++ks_) {
            int slot = (ks_ * 4 + quad) ^ (l15 & 7);
            bfrag a[2], b[4];
            #pragma unroll
            for (int i = 0; i < 2; ++i)
                a[i] = *(const bfrag*)&sA[(wave * 32 + i * 16 + l15) * 64 + slot * 8];
            #pragma unroll
            for (int nt = 0; nt < 4; ++nt)
                b[nt] = *(const bfrag*)&sB[(nt * 16 + l15) * 64 + slot * 8];
            #pragma unroll
            for (int i = 0; i < 2; ++i)
                #pragma unroll
                for (int nt = 0; nt < 4; ++nt)
                    acc[i][nt] = __builtin_amdgcn_mfma_f32_16x16x32_bf16(a[i], b[nt], acc[i][nt], 0, 0, 0);
        }
        __syncthreads();
    }

    // ---- epilogue: bias, ks2 reduction, LDS transpose, coalesced stores ----
    const int bb = row0 >> 10, t0 = row0 & 1023;
    float bvv[4];
    #pragma unroll
    for (int nt = 0; nt < 4; ++nt) bvv[nt] = bias[col0 + nt * 16 + l15];
    float wmv[4];
    #pragma unroll
    for (int nt = 0; nt < 4; ++nt) wmv[nt] = wm[nt * 16 + l15] * SC2;

    float part[2][4];
    #pragma unroll
    for (int i = 0; i < 2; ++i)
        #pragma unroll
        for (int r = 0; r < 4; ++r) part[i][r] = 0.f;

    // smem reuse: eT[col(d)][t] bf16, stride 132 (2-way banks = free)
    unsigned short* eT = smem;
    #pragma unroll
    for (int i = 0; i < 2; ++i) {
        int tr = wave * 32 + i * 16 + quad * 4;
        #pragma unroll
        for (int nt = 0; nt < 4; ++nt) {
            int col = nt * 16 + l15;
            float v0 = acc[i][nt][0] + bvv[nt], v1 = acc[i][nt][1] + bvv[nt];
            float v2 = acc[i][nt][2] + bvv[nt], v3 = acc[i][nt][3] + bvv[nt];
            part[i][0] = fmaf(wmv[nt], v0, part[i][0]);
            part[i][1] = fmaf(wmv[nt], v1, part[i][1]);
            part[i][2] = fmaf(wmv[nt], v2, part[i][2]);
            part[i][3] = fmaf(wmv[nt], v3, part[i][3]);
            *(unsigned*)&eT[col * 132 + tr]     = pack2rne(v0, v1);
            *(unsigned*)&eT[col * 132 + tr + 2] = pack2rne(v2, v3);
        }
    }
    // ks2: reduce over d (16 lanes x 4 nt already folded)
    #pragma unroll
    for (int i = 0; i < 2; ++i)
        #pragma unroll
        for (int r = 0; r < 4; ++r) {
            float p = part[i][r];
            p += __shfl_xor(p, 1); p += __shfl_xor(p, 2);
            p += __shfl_xor(p, 4); p += __shfl_xor(p, 8);
            if (l15 == 0)
                ks2[(size_t)(bb * HH + h) * TT + t0 + wave * 32 + i * 16 + quad * 4 + r] = p;
        }
    __syncthreads();
    // coalesced swizzled stores: 64 d-rows x 16 segs of 16B
    unsigned short* kxbase = kxTg + ((size_t)(bb * HH + h) * 64) * TT;
    #pragma unroll
    for (int it = 0; it < 4; ++it) {
        int task = it * 256 + tid;
        int col = task >> 4, seg = task & 15;       // col = d
        uint4 v = *(const uint4*)&eT[col * 132 + seg * 8];
        int g = (t0 >> 3) + seg;
        int p = g ^ (col & 7);
        *(uint4*)(kxbase + (size_t)col * TT + p * 8) = v;
    }
}

// ---- K5: node-curve attention. 1 block per (b,h). --------------------------
// Exact per-k weights at 128 qs-nodes; MFMA over k; Z via ones B-frag.
__global__ __launch_bounds__(256) void attn_nodes_kernel(
    const unsigned short* __restrict__ kxTg, const float* __restrict__ qs2,
    const float* __restrict__ ks2, float* __restrict__ node_out,
    float* __restrict__ mn2, float* __restrict__ inv127)
{
    __shared__ __align__(16) unsigned short kxT[64 * 256];  // 32 KB
    __shared__ float ksc[1024];
    __shared__ float redl[8];
    const int bh = blockIdx.x;
    const int tid = threadIdx.x, lane = tid & 63, wave = tid >> 6;
    const int l15 = lane & 15, quad = lane >> 4;

    // stage ks, reduce qs min/max
    ((float4*)ksc)[tid] = ((const float4*)(ks2 + (size_t)bh * TT))[tid];
    float4 q4 = ((const float4*)(qs2 + (size_t)bh * TT))[tid];
    float mn = fminf(fminf(q4.x, q4.y), fminf(q4.z, q4.w));
    float mx = fmaxf(fmaxf(q4.x, q4.y), fmaxf(q4.z, q4.w));
    #pragma unroll
    for (int off = 32; off > 0; off >>= 1) {
        mn = fminf(mn, __shfl_xor(mn, off));
        mx = fmaxf(mx, __shfl_xor(mx, off));
    }
    if (lane == 0) { redl[wave] = mn; redl[4 + wave] = mx; }
    __syncthreads();
    const float mnv = fminf(fminf(redl[0], redl[1]), fminf(redl[2], redl[3]));
    const float mxv = fmaxf(fmaxf(redl[4], redl[5]), fmaxf(redl[6], redl[7]));
    if (tid == 0) {
        mn2[bh] = mnv;
        inv127[bh] = 127.f / fmaxf(mxv - mnv, 1e-12f);
    }
    const float h2v = (mxv - mnv) * (1.f / 127.f);
    const float zA = mnv + (wave * 16 + l15) * h2v;   // node for ngrp 0
    const float zB = zA + 64.f * h2v;                 // node for ngrp 1

    const unsigned short* kxbase = kxTg + (size_t)bh * 64 * TT;
    facc acc[2][4]; facc accZ[2];
    #pragma unroll
    for (int g = 0; g < 2; ++g) {
        #pragma unroll
        for (int i = 0; i < 4; ++i) { acc[g][i][0]=0.f; acc[g][i][1]=0.f; acc[g][i][2]=0.f; acc[g][i][3]=0.f; }
        accZ[g][0]=0.f; accZ[g][1]=0.f; accZ[g][2]=0.f; accZ[g][3]=0.f;
    }
    bfrag ones;
    #pragma unroll
    for (int j = 0; j < 8; ++j) ones[j] = (short)0x3F80;

    for (int ck = 0; ck < 4; ++ck) {
        #pragma unroll
        for (int it = 0; it < 8; ++it) {
            int g = it * 256 + tid;
            int d = g >> 5, j = g & 31;
            gl2lds16(kxbase + (size_t)d * TT + ck * 256 + j * 8, &kxT[g * 8]);
        }
        __syncthreads();
        #pragma unroll
        for (int kst = 0; kst < 8; ++kst) {
            const float* kvp = &ksc[ck * 256 + kst * 32 + quad * 8];
            float4 kv0 = *(const float4*)kvp;
            float4 kv1 = *(const float4*)(kvp + 4);
            int slot = (kst * 4 + quad) ^ (l15 & 7);
            bfrag bf_[4];
            #pragma unroll
            for (int dt = 0; dt < 4; ++dt)
                bf_[dt] = *(const bfrag*)&kxT[(dt * 16 + l15) * 256 + slot * 8];
            #pragma unroll
            for (int g = 0; g < 2; ++g) {
                float z = g ? zB : zA;
                union { unsigned u[4]; bfrag f; } afu;
                afu.u[0] = pack2hu(wfun(z + kv0.x), wfun(z + kv0.y));
                afu.u[1] = pack2hu(wfun(z + kv0.z), wfun(z + kv0.w));
                afu.u[2] = pack2hu(wfun(z + kv1.x), wfun(z + kv1.y));
                afu.u[3] = pack2hu(wfun(z + kv1.z), wfun(z + kv1.w));
                #pragma unroll
                for (int dt = 0; dt < 4; ++dt)
                    acc[g][dt] = __builtin_amdgcn_mfma_f32_16x16x32_bf16(afu.f, bf_[dt], acc[g][dt], 0, 0, 0);
                accZ[g] = __builtin_amdgcn_mfma_f32_16x16x32_bf16(afu.f, ones, accZ[g], 0, 0, 0);
            }
        }
        __syncthreads();
    }
    // store node_out[bh][node][NW]
    float* ob = node_out + (size_t)bh * NND * NW;
    #pragma unroll
    for (int g = 0; g < 2; ++g) {
        #pragma unroll
        for (int r = 0; r < 4; ++r) {
            int node = g * 64 + wave * 16 + quad * 4 + r;
            #pragma unroll
            for (int dt = 0; dt < 4; ++dt)
                ob[(size_t)node * NW + dt * 16 + l15] = acc[g][dt][r];
            if (l15 == 0) ob[(size_t)node * NW + 64] = accZ[g][r];
        }
    }
}

// ---- K6: cubic interpolation -> attb bf16 (swizzled, gemm2 A-format) ----------
__global__ __launch_bounds__(256) void interp_kernel(
    const float* __restrict__ qs2, const float* __restrict__ node_out,
    const float* __restrict__ mn2, const float* __restrict__ inv127,
    unsigned short* __restrict__ attb)
{
    const int tid = threadIdx.x, lane = tid & 63, wave = tid >> 6;
    const int row = blockIdx.x * 4 + wave;
    const int b = row >> 10, t = row & 1023;
    const int hh2 = lane >> 5, dp = lane & 31;
    #pragma unroll
    for (int h0 = 0; h0 < 8; h0 += 2) {
        const int hh = h0 + hh2;
        const int bh = b * HH + hh;
        float qv = qs2[(size_t)bh * TT + t];
        float u = (qv - mn2[bh]) * inv127[bh];
        int i = (int)floorf(u) - 1;
        i = i < 0 ? 0 : (i > NND - 4 ? NND - 4 : i);
        float s = u - (float)i;
        float s1 = s - 1.f, s2 = s - 2.f, s3 = s - 3.f;
        float w0 = -s1 * s2 * s3 * (1.f / 6.f);
        float w1 = s * s2 * s3 * 0.5f;
        float w2 = -s * s1 * s3 * 0.5f;
        float w3 = s * s1 * s2 * (1.f / 6.f);
        const float* base = node_out + ((size_t)bh * NND + i) * NW;
        float nx = 0.f, ny = 0.f, zz = 0.f;
        {
            float2 v0 = *(const float2*)(base + 2 * dp);
            float2 v1 = *(const float2*)(base + NW + 2 * dp);
            float2 v2 = *(const float2*)(base + 2 * NW + 2 * dp);
            float2 v3 = *(const float2*)(base + 3 * NW + 2 * dp);
            nx = w0 * v0.x + w1 * v1.x + w2 * v2.x + w3 * v3.x;
            ny = w0 * v0.y + w1 * v1.y + w2 * v2.y + w3 * v3.y;
            zz = w0 * base[64] + w1 * base[NW + 64] + w2 * base[2 * NW + 64] + w3 * base[3 * NW + 64];
        }
        float rz = __builtin_amdgcn_rcpf(zz);
        unsigned pk = pack2rne(nx * rz, ny * rz);
        int col = hh * 64 + 2 * dp;
        int p = (col >> 3) ^ (row & 7);
        *(unsigned*)&attb[(size_t)row * DDIM + p * 8 + (col & 7)] = pk;
    }
}

// ---- K7: GEMM2 proj = attb @ WpT + bp (fp32 out). Tile 128 x 64, BK=64. -------
__global__ __launch_bounds__(256) void gemm2_kernel(
    const unsigned short* __restrict__ A, const unsigned short* __restrict__ B,
    const float* __restrict__ bias, float* __restrict__ Cf)
{
    __shared__ __align__(16) unsigned short sA[128 * 64];
    __shared__ __align__(16) unsigned short sB[64 * 64];
    const int tid = threadIdx.x, lane = tid & 63, wave = tid >> 6;
    const int l15 = lane & 15, quad = lane >> 4;
    const int col0 = blockIdx.x * 64, row0 = blockIdx.y * 128;

    facc acc[2][4];
    #pragma unroll
    for (int i = 0; i < 2; ++i)
        #pragma unroll
        for (int j = 0; j < 4; ++j) { acc[i][j][0]=0.f; acc[i][j][1]=0.f; acc[i][j][2]=0.f; acc[i][j][3]=0.f; }

    for (int k0 = 0; k0 < 512; k0 += 64) {
        #pragma unroll
        for (int it = 0; it < 4; ++it) {
            int g = it * 256 + tid;
            int r = g >> 3, kg = g & 7;
            gl2lds16(A + (size_t)(row0 + r) * 512 + k0 + kg * 8, &sA[g * 8]);
        }
        #pragma unroll
        for (int it = 0; it < 2; ++it) {
            int g = it * 256 + tid;
            int r = g >> 3, kg = g & 7;
            gl2lds16(B + (size_t)(col0 + r) * 512 + k0 + kg * 8, &sB[g * 8]);
        }
        __syncthreads();
        #pragma unroll
        for (int ks_ = 0; ks_ < 2; ++ks_) {
            int slot = (ks_ * 4 + quad) ^ (l15 & 7);
            bfrag a[2], b[4];
            #pragma unroll
            for (int i = 0; i < 2; ++i)
                a[i] = *(const bfrag*)&sA[(wave * 32 + i * 16 + l15) * 64 + slot * 8];
            #pragma unroll
            for (int nt = 0; nt < 4; ++nt)
                b[nt] = *(const bfrag*)&sB[(nt * 16 + l15) * 64 + slot * 8];
            #pragma unroll
            for (int i = 0; i < 2; ++i)
                #pragma unroll
                for (int nt = 0; nt < 4; ++nt)
                    acc[i][nt] = __builtin_amdgcn_mfma_f32_16x16x32_bf16(a[i], b[nt], acc[i][nt], 0, 0, 0);
        }
        __syncthreads();
    }
    #pragma unroll
    for (int i = 0; i < 2; ++i) {
        int grow = row0 + wave * 32 + i * 16 + quad * 4;
        #pragma unroll
        for (int nt = 0; nt < 4; ++nt) {
            int col = col0 + nt * 16 + l15;
            float bv = bias[col];
            #pragma unroll
            for (int r = 0; r < 4; ++r)
                Cf[(size_t)(grow + r) * DDIM + col] = acc[i][nt][r] + bv;
        }
    }
}

// ---- K8: residual + LayerNorm (wave per row, float4) --------------------------
__global__ __launch_bounds__(256) void ln_kernel(
    const float* __restrict__ x, const float* __restrict__ proj,
    const float* __restrict__ g, const float* __restrict__ bet,
    float* __restrict__ out)
{
    const int tid = threadIdx.x, lane = tid & 63, wave = tid >> 6;
    const int row = blockIdx.x * 4 + wave;
    const float4* xr = (const float4*)(x + (size_t)row * DDIM);
    const float4* pr = (const float4*)(proj + (size_t)row * DDIM);
    float4 a0 = xr[lane * 2], a1 = xr[lane * 2 + 1];
    float4 p0 = pr[lane * 2], p1 = pr[lane * 2 + 1];
    float y[8] = {a0.x + p0.x, a0.y + p0.y, a0.z + p0.z, a0.w + p0.w,
                  a1.x + p1.x, a1.y + p1.y, a1.z + p1.z, a1.w + p1.w};
    float s = 0.f, s2 = 0.f;
    #pragma unroll
    for (int i = 0; i < 8; ++i) { s += y[i]; s2 = fmaf(y[i], y[i], s2); }
    #pragma unroll
    for (int off = 32; off > 0; off >>= 1) {
        s += __shfl_xor(s, off);
        s2 += __shfl_xor(s2, off);
    }
    float mu = s * (1.f / 512.f);
    float var = s2 * (1.f / 512.f) - mu * mu;
    float inv = rsqrtf(var + 1e-5f);
    const float4* gp = (const float4*)(g + lane * 8);
    const float4* bp = (const float4*)(bet + lane * 8);
    float4 g0 = gp[0], g1 = gp[1], b0 = bp[0], b1 = bp[1];
    float4 o0, o1;
    o0.x = (y[0] - mu) * inv * g0.x + b0.x; o0.y = (y[1] - mu) * inv * g0.y + b0.y;
    o0.z = (y[2] - mu) * inv * g0.z + b0.z; o0.w = (y[3] - mu) * inv * g0.w + b0.w;
    o1.x = (y[4] - mu) * inv * g1.x + b1.x; o1.y = (y[5] - mu) * inv * g1.y + b1.y;
    o1.z = (y[6] - mu) * inv * g1.z + b1.z; o1.w = (y[7] - mu) * inv * g1.w + b1.w;
    float4* op = (float4*)(out + (size_t)row * DDIM);
    op[lane * 2] = o0; op[lane * 2 + 1] = o1;
}

// ---- launch -------------------------------------------------------------------
extern "C" void kernel_launch(void* const* d_in, const int* in_sizes, int n_in,
                              void* d_out, int out_size, void* d_ws, size_t ws_size,
                              hipStream_t stream)
{
    const float* x    = (const float*)d_in[0];
    const float* Wq   = (const float*)d_in[1];
    const float* bq   = (const float*)d_in[2];
    const float* Wk   = (const float*)d_in[3];
    const float* bk   = (const float*)d_in[4];
    const float* Wp   = (const float*)d_in[5];
    const float* bp   = (const float*)d_in[6];
    const float* wm   = (const float*)d_in[7];
    const float* ln_g = (const float*)d_in[8];
    const float* ln_b = (const float*)d_in[9];
    float* out = (float*)d_out;

    float* ws = (float*)d_ws;
    float*          vq2  = ws;                                   // 4096
    float*          qsb2 = ws + 4096;                            // 8
    unsigned short* WkT  = (unsigned short*)(ws + 4352);         // 131072 f
    unsigned short* WpT  = (unsigned short*)(ws + 135424);       // 131072 f
    unsigned short* xb   = (unsigned short*)(ws + 266496);       // 2097152 f
    unsigned short* kxTg = (unsigned short*)(ws + 2363648);      // 2097152 f
    float*          qs2  = ws + 4460800;                         // 65536
    float*          ks2  = ws + 4526336;                         // 65536
    unsigned short* attb = (unsigned short*)(ws + 4591872);      // 2097152 f
    float*          ndo  = ws + 6689024;                         // 589824
    float*          mn2  = ws + 7278848;                         // 64
    float*          i127 = ws + 7278912;                         // 64
    float*          proj = ws + 266496;   // aliases xb+kxTg (dead by gemm2)

    prep_kernel<<<16, 256, 0, stream>>>(Wq, bq, wm, vq2, qsb2);
    trans_kernel<<<dim3(8, 8, 2), 256, 0, stream>>>(Wk, Wp, WkT, WpT);
    preconv_kernel<<<2048, 256, 0, stream>>>(x, vq2, qsb2, xb, qs2);
    gemm1_kernel<<<dim3(8, 64), 256, 0, stream>>>(xb, WkT, bk, kxTg, ks2, wm);
    attn_nodes_kernel<<<64, 256, 0, stream>>>(kxTg, qs2, ks2, ndo, mn2, i127);
    interp_kernel<<<2048, 256, 0, stream>>>(qs2, ndo, mn2, i127, attb);
    gemm2_kernel<<<dim3(8, 64), 256, 0, stream>>>(attb, WpT, bp, proj);
    ln_kernel<<<2048, 256, 0, stream>>>(x, proj, ln_g, ln_b, out);
}

// Round 5
// 151.392 us; speedup vs baseline: 3.3527x; 1.0480x over previous
//
#include <hip/hip_runtime.h>
#include <cstddef>

#define TT 1024
#define DDIM 512
#define HH 8
#define NND 128          // interpolation nodes per (b,h)
#define NW 72            // node_out row width: 64 d + Z at [64], padded

typedef __attribute__((ext_vector_type(8))) short bfrag;   // 8 bf16 (4 VGPRs)
typedef __attribute__((ext_vector_type(4))) float facc;    // 4 fp32 acc

#define SC2   2.8853900817779268f   // 2*log2(e)
#define L2E   1.4426950408889634f

static __device__ __forceinline__ unsigned bfrne(float f) {
    unsigned u = __float_as_uint(f);
    return (u + 0x7fffu + ((u >> 16) & 1u)) >> 16;
}
static __device__ __forceinline__ unsigned pack2rne(float a, float b) {
    return bfrne(a) | (bfrne(b) << 16);
}
static __device__ __forceinline__ unsigned pack2hu(float a, float b) {
    return ((__float_as_uint(a) + 0x8000u) >> 16) |
           ((__float_as_uint(b) + 0x8000u) & 0xffff0000u);
}
static __device__ __forceinline__ void gl2lds16(const void* g, void* l) {
    __builtin_amdgcn_global_load_lds(
        (const __attribute__((address_space(1))) unsigned int*)g,
        (__attribute__((address_space(3))) unsigned int*)l, 16, 0, 0);
}
// w(z2) = exp(tanh(z)) with z2 = 2*log2e*z pre-scaled
static __device__ __forceinline__ float wfun(float z2) {
    float t = __builtin_amdgcn_exp2f(z2);
    float r = __builtin_amdgcn_rcpf(t + 1.f);
    return __builtin_amdgcn_exp2f(fmaf(r, -2.f * L2E, L2E));
}

// ---- K1: fused prepare ---------------------------------------------------------
// blocks [0,2048): x -> xb bf16 swizzled
// blocks [2048,2176): Wk/Wp -> WkT/WpT [n][k] bf16 swizzled
// blocks [2176,2192): vq2b[h][k] = bf16((Wq[:,h*64:]@wm[64:])*SC2); qsb2
__global__ __launch_bounds__(256) void prepare_kernel(
    const float* __restrict__ x, const float* __restrict__ Wk,
    const float* __restrict__ Wp, const float* __restrict__ Wq,
    const float* __restrict__ bq, const float* __restrict__ wm,
    unsigned short* __restrict__ xb, unsigned short* __restrict__ WkT,
    unsigned short* __restrict__ WpT, unsigned short* __restrict__ vq2b,
    float* __restrict__ qsb2)
{
    const int bx = blockIdx.x, tid = threadIdx.x;
    if (bx < 2048) {
        const int lane = tid & 63, wave = tid >> 6;
        const int row = bx * 4 + wave;
        const float4* xr = (const float4*)(x + (size_t)row * DDIM);
        float4 x0 = xr[lane * 2], x1 = xr[lane * 2 + 1];
        uint4 st;
        st.x = pack2rne(x0.x, x0.y); st.y = pack2rne(x0.z, x0.w);
        st.z = pack2rne(x1.x, x1.y); st.w = pack2rne(x1.z, x1.w);
        int p = lane ^ (row & 7);
        *(uint4*)(xb + (size_t)row * DDIM + p * 8) = st;
    } else if (bx < 2176) {
        int idx = bx - 2048;
        const float* src = (idx & 64) ? Wp : Wk;
        unsigned short* dst = (idx & 64) ? WpT : WkT;
        idx &= 63;
        const int n0 = (idx & 7) * 64, k0 = (idx >> 3) * 64;
        __shared__ float sT[64][65];
        #pragma unroll
        for (int it = 0; it < 4; ++it) {
            int task = it * 256 + tid;
            int kr = task >> 4, c4 = (task & 15) * 4;
            float4 v = *(const float4*)(src + (size_t)(k0 + kr) * DDIM + n0 + c4);
            sT[kr][c4] = v.x; sT[kr][c4 + 1] = v.y; sT[kr][c4 + 2] = v.z; sT[kr][c4 + 3] = v.w;
        }
        __syncthreads();
        #pragma unroll
        for (int it = 0; it < 2; ++it) {
            int task = it * 256 + tid;
            int n = task >> 3, kg = task & 7;
            unsigned u[4];
            #pragma unroll
            for (int jj = 0; jj < 4; ++jj)
                u[jj] = pack2rne(sT[kg * 8 + jj * 2][n], sT[kg * 8 + jj * 2 + 1][n]);
            int p = ((k0 >> 3) + kg) ^ (n & 7);
            uint4 st; st.x = u[0]; st.y = u[1]; st.z = u[2]; st.w = u[3];
            *(uint4*)(dst + (size_t)(n0 + n) * DDIM + p * 8) = st;
        }
    } else {
        int idx = (bx - 2176) * 256 + tid;   // 0..4095
        int h = idx >> 9, d = idx & 511;
        float s = 0.f;
        #pragma unroll 8
        for (int j = 0; j < 64; ++j)
            s = fmaf(Wq[(size_t)d * DDIM + h * 64 + j], wm[64 + j], s);
        vq2b[h * DDIM + d] = (unsigned short)bfrne(s * SC2);
        if (idx < HH) {
            float sb = 0.f;
            for (int j = 0; j < 64; ++j)
                sb = fmaf(bq[idx * 64 + j], wm[64 + j], sb);
            qsb2[idx] = sb * SC2;
        }
    }
}

// ---- K2: GEMM1 kx = xb @ WkT + bk. Tile 128 t x 64 d (one head), BK=64. -------
// Fused: qs2 via extra MFMA with vq2b B-frag; ks2 reduction; kxT transpose.
__global__ __launch_bounds__(256) void gemm1_kernel(
    const unsigned short* __restrict__ A, const unsigned short* __restrict__ B,
    const float* __restrict__ bias, unsigned short* __restrict__ kxTg,
    float* __restrict__ ks2, const float* __restrict__ wm,
    const unsigned short* __restrict__ vq2b, const float* __restrict__ qsb2,
    float* __restrict__ qs2)
{
    __shared__ __align__(16) unsigned short smem[12288];   // sA 8192 | sB 4096
    unsigned short* sA = smem;
    unsigned short* sB = smem + 8192;
    const int tid = threadIdx.x, lane = tid & 63, wave = tid >> 6;
    const int l15 = lane & 15, quad = lane >> 4;
    const int h = blockIdx.x, row0 = blockIdx.y * 128;
    const int col0 = h * 64;

    facc acc[2][4]; facc accq[2];
    #pragma unroll
    for (int i = 0; i < 2; ++i) {
        #pragma unroll
        for (int j = 0; j < 4; ++j) { acc[i][j][0]=0.f; acc[i][j][1]=0.f; acc[i][j][2]=0.f; acc[i][j][3]=0.f; }
        accq[i][0]=0.f; accq[i][1]=0.f; accq[i][2]=0.f; accq[i][3]=0.f;
    }

    for (int k0 = 0; k0 < 512; k0 += 64) {
        #pragma unroll
        for (int it = 0; it < 4; ++it) {
            int g = it * 256 + tid;
            int r = g >> 3, kg = g & 7;
            gl2lds16(A + (size_t)(row0 + r) * 512 + k0 + kg * 8, &sA[g * 8]);
        }
        #pragma unroll
        for (int it = 0; it < 2; ++it) {
            int g = it * 256 + tid;
            int r = g >> 3, kg = g & 7;
            gl2lds16(B + (size_t)(col0 + r) * 512 + k0 + kg * 8, &sB[g * 8]);
        }
        __syncthreads();
        #pragma unroll
        for (int ks_ = 0; ks_ < 2; ++ks_) {
            int slot = (ks_ * 4 + quad) ^ (l15 & 7);
            bfrag a[2], b[4];
            #pragma unroll
            for (int i = 0; i < 2; ++i)
                a[i] = *(const bfrag*)&sA[(wave * 32 + i * 16 + l15) * 64 + slot * 8];
            #pragma unroll
            for (int nt = 0; nt < 4; ++nt)
                b[nt] = *(const bfrag*)&sB[(nt * 16 + l15) * 64 + slot * 8];
            // qs fragment: every n-column = vq2 slice (logical k matches a[] granule)
            bfrag bvq = *(const bfrag*)(vq2b + h * 512 + k0 + ks_ * 32 + quad * 8);
            #pragma unroll
            for (int i = 0; i < 2; ++i) {
                #pragma unroll
                for (int nt = 0; nt < 4; ++nt)
                    acc[i][nt] = __builtin_amdgcn_mfma_f32_16x16x32_bf16(a[i], b[nt], acc[i][nt], 0, 0, 0);
                accq[i] = __builtin_amdgcn_mfma_f32_16x16x32_bf16(a[i], bvq, accq[i], 0, 0, 0);
            }
        }
        __syncthreads();
    }

    // ---- epilogue: bias, qs2/ks2, LDS transpose, coalesced swizzled stores ----
    const int bb = row0 >> 10, t0 = row0 & 1023;
    const float qsbh = qsb2[h];
    float bvv[4], wmv[4];
    #pragma unroll
    for (int nt = 0; nt < 4; ++nt) {
        bvv[nt] = bias[col0 + nt * 16 + l15];
        wmv[nt] = wm[nt * 16 + l15] * SC2;
    }
    float part[2][4];
    #pragma unroll
    for (int i = 0; i < 2; ++i)
        #pragma unroll
        for (int r = 0; r < 4; ++r) part[i][r] = 0.f;

    // smem reuse: eT[d][t] bf16, stride 136 (272B: 16B-aligned, 4-bank step)
    unsigned short* eT = smem;
    #pragma unroll
    for (int i = 0; i < 2; ++i) {
        int tr = wave * 32 + i * 16 + quad * 4;
        #pragma unroll
        for (int nt = 0; nt < 4; ++nt) {
            int col = nt * 16 + l15;
            float v0 = acc[i][nt][0] + bvv[nt], v1 = acc[i][nt][1] + bvv[nt];
            float v2 = acc[i][nt][2] + bvv[nt], v3 = acc[i][nt][3] + bvv[nt];
            part[i][0] = fmaf(wmv[nt], v0, part[i][0]);
            part[i][1] = fmaf(wmv[nt], v1, part[i][1]);
            part[i][2] = fmaf(wmv[nt], v2, part[i][2]);
            part[i][3] = fmaf(wmv[nt], v3, part[i][3]);
            *(unsigned*)&eT[col * 136 + tr]     = pack2rne(v0, v1);
            *(unsigned*)&eT[col * 136 + tr + 2] = pack2rne(v2, v3);
        }
    }
    // ks2 (reduce over d) and qs2 (col 0 of accq, all cols identical)
    #pragma unroll
    for (int i = 0; i < 2; ++i)
        #pragma unroll
        for (int r = 0; r < 4; ++r) {
            float p = part[i][r];
            p += __shfl_xor(p, 1); p += __shfl_xor(p, 2);
            p += __shfl_xor(p, 4); p += __shfl_xor(p, 8);
            if (l15 == 0) {
                size_t o = (size_t)(bb * HH + h) * TT + t0 + wave * 32 + i * 16 + quad * 4 + r;
                ks2[o] = p;
                qs2[o] = accq[i][r] + qsbh;
            }
        }
    __syncthreads();
    unsigned short* kxbase = kxTg + ((size_t)(bb * HH + h) * 64) * TT;
    #pragma unroll
    for (int it = 0; it < 4; ++it) {
        int task = it * 256 + tid;
        int col = task >> 4, seg = task & 15;       // col = d
        uint4 v = *(const uint4*)&eT[col * 136 + seg * 8];
        int g = (t0 >> 3) + seg;
        int p = g ^ (col & 7);
        *(uint4*)(kxbase + (size_t)col * TT + p * 8) = v;
    }
}

// ---- K3: node-curve attention. 1 block per (b,h). -----------------------------
__global__ __launch_bounds__(256) void attn_nodes_kernel(
    const unsigned short* __restrict__ kxTg, const float* __restrict__ qs2,
    const float* __restrict__ ks2, float* __restrict__ node_out,
    float* __restrict__ mn2, float* __restrict__ inv127)
{
    __shared__ __align__(16) unsigned short kxT[64 * 256];  // 32 KB
    __shared__ float ksc[1024];
    __shared__ float redl[8];
    const int bh = blockIdx.x;
    const int tid = threadIdx.x, lane = tid & 63, wave = tid >> 6;
    const int l15 = lane & 15, quad = lane >> 4;

    ((float4*)ksc)[tid] = ((const float4*)(ks2 + (size_t)bh * TT))[tid];
    float4 q4 = ((const float4*)(qs2 + (size_t)bh * TT))[tid];
    float mn = fminf(fminf(q4.x, q4.y), fminf(q4.z, q4.w));
    float mx = fmaxf(fmaxf(q4.x, q4.y), fmaxf(q4.z, q4.w));
    #pragma unroll
    for (int off = 32; off > 0; off >>= 1) {
        mn = fminf(mn, __shfl_xor(mn, off));
        mx = fmaxf(mx, __shfl_xor(mx, off));
    }
    if (lane == 0) { redl[wave] = mn; redl[4 + wave] = mx; }
    __syncthreads();
    const float mnv = fminf(fminf(redl[0], redl[1]), fminf(redl[2], redl[3]));
    const float mxv = fmaxf(fmaxf(redl[4], redl[5]), fmaxf(redl[6], redl[7]));
    if (tid == 0) {
        mn2[bh] = mnv;
        inv127[bh] = 127.f / fmaxf(mxv - mnv, 1e-12f);
    }
    const float h2v = (mxv - mnv) * (1.f / 127.f);
    const float zA = mnv + (wave * 16 + l15) * h2v;
    const float zB = zA + 64.f * h2v;

    const unsigned short* kxbase = kxTg + (size_t)bh * 64 * TT;
    facc acc[2][4]; facc accZ[2];
    #pragma unroll
    for (int g = 0; g < 2; ++g) {
        #pragma unroll
        for (int i = 0; i < 4; ++i) { acc[g][i][0]=0.f; acc[g][i][1]=0.f; acc[g][i][2]=0.f; acc[g][i][3]=0.f; }
        accZ[g][0]=0.f; accZ[g][1]=0.f; accZ[g][2]=0.f; accZ[g][3]=0.f;
    }
    bfrag ones;
    #pragma unroll
    for (int j = 0; j < 8; ++j) ones[j] = (short)0x3F80;

    for (int ck = 0; ck < 4; ++ck) {
        #pragma unroll
        for (int it = 0; it < 8; ++it) {
            int g = it * 256 + tid;
            int d = g >> 5, j = g & 31;
            gl2lds16(kxbase + (size_t)d * TT + ck * 256 + j * 8, &kxT[g * 8]);
        }
        __syncthreads();
        #pragma unroll
        for (int kst = 0; kst < 8; ++kst) {
            const float* kvp = &ksc[ck * 256 + kst * 32 + quad * 8];
            float4 kv0 = *(const float4*)kvp;
            float4 kv1 = *(const float4*)(kvp + 4);
            int slot = (kst * 4 + quad) ^ (l15 & 7);
            bfrag bf_[4];
            #pragma unroll
            for (int dt = 0; dt < 4; ++dt)
                bf_[dt] = *(const bfrag*)&kxT[(dt * 16 + l15) * 256 + slot * 8];
            #pragma unroll
            for (int g = 0; g < 2; ++g) {
                float z = g ? zB : zA;
                union { unsigned u[4]; bfrag f; } afu;
                afu.u[0] = pack2hu(wfun(z + kv0.x), wfun(z + kv0.y));
                afu.u[1] = pack2hu(wfun(z + kv0.z), wfun(z + kv0.w));
                afu.u[2] = pack2hu(wfun(z + kv1.x), wfun(z + kv1.y));
                afu.u[3] = pack2hu(wfun(z + kv1.z), wfun(z + kv1.w));
                #pragma unroll
                for (int dt = 0; dt < 4; ++dt)
                    acc[g][dt] = __builtin_amdgcn_mfma_f32_16x16x32_bf16(afu.f, bf_[dt], acc[g][dt], 0, 0, 0);
                accZ[g] = __builtin_amdgcn_mfma_f32_16x16x32_bf16(afu.f, ones, accZ[g], 0, 0, 0);
            }
        }
        __syncthreads();
    }
    float* ob = node_out + (size_t)bh * NND * NW;
    #pragma unroll
    for (int g = 0; g < 2; ++g) {
        #pragma unroll
        for (int r = 0; r < 4; ++r) {
            int node = g * 64 + wave * 16 + quad * 4 + r;
            #pragma unroll
            for (int dt = 0; dt < 4; ++dt)
                ob[(size_t)node * NW + dt * 16 + l15] = acc[g][dt][r];
            if (l15 == 0) ob[(size_t)node * NW + 64] = accZ[g][r];
        }
    }
}

// ---- K4: cubic interpolation -> attb bf16 (swizzled, gemm2 A-format) ----------
__global__ __launch_bounds__(256) void interp_kernel(
    const float* __restrict__ qs2, const float* __restrict__ node_out,
    const float* __restrict__ mn2, const float* __restrict__ inv127,
    unsigned short* __restrict__ attb)
{
    const int tid = threadIdx.x, lane = tid & 63, wave = tid >> 6;
    const int row = blockIdx.x * 4 + wave;
    const int b = row >> 10, t = row & 1023;
    const int hh2 = lane >> 5, dp = lane & 31;
    #pragma unroll
    for (int h0 = 0; h0 < 8; h0 += 2) {
        const int hh = h0 + hh2;
        const int bh = b * HH + hh;
        float qv = qs2[(size_t)bh * TT + t];
        float u = (qv - mn2[bh]) * inv127[bh];
        int i = (int)floorf(u) - 1;
        i = i < 0 ? 0 : (i > NND - 4 ? NND - 4 : i);
        float s = u - (float)i;
        float s1 = s - 1.f, s2 = s - 2.f, s3 = s - 3.f;
        float w0 = -s1 * s2 * s3 * (1.f / 6.f);
        float w1 = s * s2 * s3 * 0.5f;
        float w2 = -s * s1 * s3 * 0.5f;
        float w3 = s * s1 * s2 * (1.f / 6.f);
        const float* base = node_out + ((size_t)bh * NND + i) * NW;
        float2 v0 = *(const float2*)(base + 2 * dp);
        float2 v1 = *(const float2*)(base + NW + 2 * dp);
        float2 v2 = *(const float2*)(base + 2 * NW + 2 * dp);
        float2 v3 = *(const float2*)(base + 3 * NW + 2 * dp);
        float nx = w0 * v0.x + w1 * v1.x + w2 * v2.x + w3 * v3.x;
        float ny = w0 * v0.y + w1 * v1.y + w2 * v2.y + w3 * v3.y;
        float zz = w0 * base[64] + w1 * base[NW + 64] + w2 * base[2 * NW + 64] + w3 * base[3 * NW + 64];
        float rz = __builtin_amdgcn_rcpf(zz);
        unsigned pk = pack2rne(nx * rz, ny * rz);
        int col = hh * 64 + 2 * dp;
        int p = (col >> 3) ^ (row & 7);
        *(unsigned*)&attb[(size_t)row * DDIM + p * 8 + (col & 7)] = pk;
    }
}

// ---- K5: GEMM2 y = x + attb@WpT + bp, bf16 out. Tile 128 x 64, BK=64. ---------
__global__ __launch_bounds__(256) void gemm2_kernel(
    const unsigned short* __restrict__ A, const unsigned short* __restrict__ B,
    const float* __restrict__ bias, const float* __restrict__ x,
    unsigned short* __restrict__ yb)
{
    __shared__ __align__(16) unsigned short smem[12288];   // sA 8192 | sB 4096
    unsigned short* sA = smem;
    unsigned short* sB = smem + 8192;
    const int tid = threadIdx.x, lane = tid & 63, wave = tid >> 6;
    const int l15 = lane & 15, quad = lane >> 4;
    const int col0 = blockIdx.x * 64, row0 = blockIdx.y * 128;

    facc acc[2][4];
    #pragma unroll
    for (int i = 0; i < 2; ++i)
        #pragma unroll
        for (int j = 0; j < 4; ++j) { acc[i][j][0]=0.f; acc[i][j][1]=0.f; acc[i][j][2]=0.f; acc[i][j][3]=0.f; }

    for (int k0 = 0; k0 < 512; k0 += 64) {
        #pragma unroll
        for (int it = 0; it < 4; ++it) {
            int g = it * 256 + tid;
            int r = g >> 3, kg = g & 7;
            gl2lds16(A + (size_t)(row0 + r) * 512 + k0 + kg * 8, &sA[g * 8]);
        }
        #pragma unroll
        for (int it = 0; it < 2; ++it) {
            int g = it * 256 + tid;
            int r = g >> 3, kg = g & 7;
            gl2lds16(B + (size_t)(col0 + r) * 512 + k0 + kg * 8, &sB[g * 8]);
        }
        __syncthreads();
        #pragma unroll
        for (int ks_ = 0; ks_ < 2; ++ks_) {
            int slot = (ks_ * 4 + quad) ^ (l15 & 7);
            bfrag a[2], b[4];
            #pragma unroll
            for (int i = 0; i < 2; ++i)
                a[i] = *(const bfrag*)&sA[(wave * 32 + i * 16 + l15) * 64 + slot * 8];
            #pragma unroll
            for (int nt = 0; nt < 4; ++nt)
                b[nt] = *(const bfrag*)&sB[(nt * 16 + l15) * 64 + slot * 8];
            #pragma unroll
            for (int i = 0; i < 2; ++i)
                #pragma unroll
                for (int nt = 0; nt < 4; ++nt)
                    acc[i][nt] = __builtin_amdgcn_mfma_f32_16x16x32_bf16(a[i], b[nt], acc[i][nt], 0, 0, 0);
        }
        __syncthreads();
    }
    // epilogue: y = x + proj + bias -> LDS (stride 72: 144B, 16B-aligned) -> uint4
    float bvv[4];
    #pragma unroll
    for (int nt = 0; nt < 4; ++nt) bvv[nt] = bias[col0 + nt * 16 + l15];
    unsigned short* yT = smem;
    #pragma unroll
    for (int i = 0; i < 2; ++i) {
        #pragma unroll
        for (int nt = 0; nt < 4; ++nt) {
            int col = nt * 16 + l15;
            #pragma unroll
            for (int r = 0; r < 4; ++r) {
                int row = wave * 32 + i * 16 + quad * 4 + r;
                float xv = x[(size_t)(row0 + row) * DDIM + col0 + col];
                float y = acc[i][nt][r] + bvv[nt] + xv;
                yT[row * 72 + col] = (unsigned short)bfrne(y);
            }
        }
    }
    __syncthreads();
    #pragma unroll
    for (int it = 0; it < 4; ++it) {
        int task = it * 256 + tid;
        int row = task >> 3, seg = task & 7;
        uint4 v = *(const uint4*)&yT[row * 72 + seg * 8];
        *(uint4*)(yb + (size_t)(row0 + row) * DDIM + col0 + seg * 8) = v;
    }
}

// ---- K6: LayerNorm over bf16 y ------------------------------------------------
__global__ __launch_bounds__(256) void ln_kernel(
    const unsigned short* __restrict__ yb, const float* __restrict__ g,
    const float* __restrict__ bet, float* __restrict__ out)
{
    const int tid = threadIdx.x, lane = tid & 63, wave = tid >> 6;
    const int row = blockIdx.x * 4 + wave;
    uint4 v = *(const uint4*)(yb + (size_t)row * DDIM + lane * 8);
    float y[8];
    y[0] = __uint_as_float(v.x << 16); y[1] = __uint_as_float(v.x & 0xffff0000u);
    y[2] = __uint_as_float(v.y << 16); y[3] = __uint_as_float(v.y & 0xffff0000u);
    y[4] = __uint_as_float(v.z << 16); y[5] = __uint_as_float(v.z & 0xffff0000u);
    y[6] = __uint_as_float(v.w << 16); y[7] = __uint_as_float(v.w & 0xffff0000u);
    float s = 0.f, s2 = 0.f;
    #pragma unroll
    for (int i = 0; i < 8; ++i) { s += y[i]; s2 = fmaf(y[i], y[i], s2); }
    #pragma unroll
    for (int off = 32; off > 0; off >>= 1) {
        s += __shfl_xor(s, off);
        s2 += __shfl_xor(s2, off);
    }
    float mu = s * (1.f / 512.f);
    float var = s2 * (1.f / 512.f) - mu * mu;
    float inv = rsqrtf(var + 1e-5f);
    const float4* gp = (const float4*)(g + lane * 8);
    const float4* bp = (const float4*)(bet + lane * 8);
    float4 g0 = gp[0], g1 = gp[1], b0 = bp[0], b1 = bp[1];
    float4 o0, o1;
    o0.x = (y[0] - mu) * inv * g0.x + b0.x; o0.y = (y[1] - mu) * inv * g0.y + b0.y;
    o0.z = (y[2] - mu) * inv * g0.z + b0.z; o0.w = (y[3] - mu) * inv * g0.w + b0.w;
    o1.x = (y[4] - mu) * inv * g1.x + b1.x; o1.y = (y[5] - mu) * inv * g1.y + b1.y;
    o1.z = (y[6] - mu) * inv * g1.z + b1.z; o1.w = (y[7] - mu) * inv * g1.w + b1.w;
    float4* op = (float4*)(out + (size_t)row * DDIM);
    op[lane * 2] = o0; op[lane * 2 + 1] = o1;
}

// ---- launch -------------------------------------------------------------------
extern "C" void kernel_launch(void* const* d_in, const int* in_sizes, int n_in,
                              void* d_out, int out_size, void* d_ws, size_t ws_size,
                              hipStream_t stream)
{
    const float* x    = (const float*)d_in[0];
    const float* Wq   = (const float*)d_in[1];
    const float* bq   = (const float*)d_in[2];
    const float* Wk   = (const float*)d_in[3];
    const float* bk   = (const float*)d_in[4];
    const float* Wp   = (const float*)d_in[5];
    const float* bp   = (const float*)d_in[6];
    const float* wm   = (const float*)d_in[7];
    const float* ln_g = (const float*)d_in[8];
    const float* ln_b = (const float*)d_in[9];
    float* out = (float*)d_out;

    float* ws = (float*)d_ws;
    float*          qsb2 = ws;                                    // 8 (pad 64)
    unsigned short* vq2b = (unsigned short*)(ws + 64);            // 4096 sh = 2048 f
    unsigned short* WkT  = (unsigned short*)(ws + 2112);          // 131072 f
    unsigned short* WpT  = (unsigned short*)(ws + 133184);        // 131072 f
    unsigned short* xb   = (unsigned short*)(ws + 264256);        // 2097152 f
    unsigned short* kxTg = (unsigned short*)(ws + 2361408);       // 2097152 f
    float*          qs2  = ws + 4458560;                          // 65536
    float*          ks2  = ws + 4524096;                          // 65536
    unsigned short* attb = (unsigned short*)(ws + 4589632);       // 2097152 f
    float*          ndo  = ws + 6686784;                          // 589824
    float*          mn2  = ws + 7276608;                          // 64
    float*          i127 = ws + 7276672;                          // 64
    unsigned short* yb   = xb;   // xb dead after gemm1; reuse for y

    prepare_kernel<<<2192, 256, 0, stream>>>(x, Wk, Wp, Wq, bq, wm,
                                             xb, WkT, WpT, vq2b, qsb2);
    gemm1_kernel<<<dim3(8, 64), 256, 0, stream>>>(xb, WkT, bk, kxTg, ks2, wm,
                                                  vq2b, qsb2, qs2);
    attn_nodes_kernel<<<64, 256, 0, stream>>>(kxTg, qs2, ks2, ndo, mn2, i127);
    interp_kernel<<<2048, 256, 0, stream>>>(qs2, ndo, mn2, i127, attb);
    gemm2_kernel<<<dim3(8, 64), 256, 0, stream>>>(attb, WpT, bp, x, yb);
    ln_kernel<<<2048, 256, 0, stream>>>(yb, ln_g, ln_b, out);
}